// Round 9
// baseline (473.985 us; speedup 1.0000x reference)
//
#include <hip/hip_runtime.h>

using u64 = unsigned long long;
typedef _Float16 f16;
using f16x8 = __attribute__((ext_vector_type(8))) _Float16;
using f16x4 = __attribute__((ext_vector_type(4))) _Float16;
using f32x4 = __attribute__((ext_vector_type(4))) float;

// ======================= Hilbert encode (Skilling) =======================
__device__ __forceinline__ int hilbert3(int X0, int X1, int X2) {
  #pragma unroll
  for (int Q = 256; Q > 1; Q >>= 1) {
    const int P = Q - 1;
    if (X0 & Q) X0 ^= P;
    int t1 = (X0 ^ X1) & P;
    if (X1 & Q) X0 ^= P; else { X0 ^= t1; X1 ^= t1; }
    int t2 = (X0 ^ X2) & P;
    if (X2 & Q) X0 ^= P; else { X0 ^= t2; X2 ^= t2; }
  }
  X1 ^= X0;
  X2 ^= X1;
  int t = 0;
  #pragma unroll
  for (int Q = 256; Q > 1; Q >>= 1) if (X2 & Q) t ^= (Q - 1);
  X0 ^= t; X1 ^= t; X2 ^= t;
  int code = 0;
  #pragma unroll
  for (int b = 8; b >= 0; b--)
    code = (code << 3) | (((X0 >> b) & 1) << 2) | (((X1 >> b) & 1) << 1) | ((X2 >> b) & 1);
  return code;
}

__device__ __forceinline__ void cswap(u64& a, u64& b, bool up) {
  if ((a > b) == up) { u64 t = a; a = b; b = t; }
}

// ======================= batch-segmented bitonic sort (round-5 config) ========
__global__ __launch_bounds__(1024) void sort_tile0(const int* __restrict__ vox,
                                                   u64* __restrict__ keys, int n,
                                                   int spanm1) {
  __shared__ u64 s[4096];
  const int base = blockIdx.x * 4096;
  const int bl = base & spanm1;
  #pragma unroll
  for (int m = 0; m < 4; m++) {
    const int e = base + threadIdx.x + m * 1024;
    const int isrc = e & (n - 1);
    const int4 c = ((const int4*)vox)[isrc];
    const unsigned code = (e < n) ? (unsigned)hilbert3(c.y, c.z, c.w)
                                  : (unsigned)hilbert3(c.w, c.z, c.y);
    s[threadIdx.x + m * 1024] =
        ((u64)(unsigned)c.x << 45) | ((u64)code << 18) | (unsigned)isrc;
  }
  __syncthreads();
  for (int k = 2; k <= 4096; k <<= 1) {
    for (int j = k >> 1; j >= 1; j >>= 1) {
      #pragma unroll
      for (int m = 0; m < 2; m++) {
        const int p = threadIdx.x + m * 1024;
        const int i = ((p & ~(j - 1)) << 1) | (p & (j - 1));
        const bool up = (((bl + i) & k) == 0);
        u64 a = s[i], b = s[i | j];
        if ((a > b) == up) { s[i] = b; s[i | j] = a; }
      }
      __syncthreads();
    }
  }
  #pragma unroll
  for (int m = 0; m < 4; m++)
    keys[base + threadIdx.x + m * 1024] = s[threadIdx.x + m * 1024];
}

template<int LEV>
__device__ __forceinline__ void gstepT(u64* __restrict__ keys, int t, int jlow,
                                       int k, int spanm1) {
  constexpr int S = 1 << LEV;
  const int i0 = ((t & ~(jlow - 1)) << LEV) | (t & (jlow - 1));
  const bool up = (((i0 & spanm1) & k) == 0);
  u64 x[S];
  #pragma unroll
  for (int m = 0; m < S; m++) x[m] = keys[i0 + (size_t)m * jlow];
  #pragma unroll
  for (int d = S >> 1; d >= 1; d >>= 1)
    #pragma unroll
    for (int m = 0; m < S; m++)
      if (!(m & d)) cswap(x[m], x[m | d], up);
  #pragma unroll
  for (int m = 0; m < S; m++) keys[i0 + (size_t)m * jlow] = x[m];
}

__global__ void bitonic_gN(u64* __restrict__ keys, int jlow, int lev, int k, int spanm1) {
  const int t = blockIdx.x * blockDim.x + threadIdx.x;
  switch (lev) {
    case 1: gstepT<1>(keys, t, jlow, k, spanm1); break;
    case 2: gstepT<2>(keys, t, jlow, k, spanm1); break;
    case 3: gstepT<3>(keys, t, jlow, k, spanm1); break;
    default: gstepT<4>(keys, t, jlow, k, spanm1); break;
  }
}

__global__ __launch_bounds__(1024) void merge_tile4(u64* __restrict__ keys, int k,
                                                    int spanm1) {
  __shared__ u64 s[4096];
  const int base = blockIdx.x * 4096;
  #pragma unroll
  for (int m = 0; m < 4; m++)
    s[threadIdx.x + m * 1024] = keys[base + threadIdx.x + m * 1024];
  __syncthreads();
  const bool up = (((base & spanm1) & k) == 0);
  for (int j = 2048; j >= 1; j >>= 1) {
    #pragma unroll
    for (int m = 0; m < 2; m++) {
      const int p = threadIdx.x + m * 1024;
      const int i = ((p & ~(j - 1)) << 1) | (p & (j - 1));
      u64 a = s[i], b = s[i | j];
      if ((a > b) == up) { s[i] = b; s[i | j] = a; }
    }
    __syncthreads();
  }
  #pragma unroll
  for (int m = 0; m < 4; m++)
    keys[base + threadIdx.x + m * 1024] = s[threadIdx.x + m * 1024];
}

// ==== permutation extraction ====
__global__ void extract_inv_k(const u64* __restrict__ keys, const float* __restrict__ pts,
                              int* __restrict__ ind, int* __restrict__ inv,
                              float* __restrict__ pts1p, int n) {
  int t = blockIdx.x * blockDim.x + threadIdx.x;
  if (t >= n) return;
  int s = (int)(keys[t] & 0x3FFFFULL);
  ind[t] = s;
  inv[s] = t;
  pts1p[t * 3 + 0] = pts[s * 3 + 0];
  pts1p[t * 3 + 1] = pts[s * 3 + 1];
  pts1p[t * 3 + 2] = pts[s * 3 + 2];
}

__global__ void finish_k(const u64* __restrict__ keys2, const int* __restrict__ inv1,
                         int* __restrict__ g2, const float* __restrict__ pts,
                         const int* __restrict__ vox, const int* __restrict__ numbs,
                         float* __restrict__ out_pts, float* __restrict__ out_vox,
                         float* __restrict__ out_nb, int n, int B) {
  int t = blockIdx.x * blockDim.x + threadIdx.x;
  if (t >= n) return;
  int s = (int)(keys2[t] & 0x3FFFFULL);
  g2[t] = inv1[s];
  out_pts[t * 3 + 0] = pts[s * 3 + 0];
  out_pts[t * 3 + 1] = pts[s * 3 + 1];
  out_pts[t * 3 + 2] = pts[s * 3 + 2];
  const int4 v = ((const int4*)vox)[s];
  out_vox[t * 4 + 0] = (float)v.x;
  out_vox[t * 4 + 1] = (float)v.y;
  out_vox[t * 4 + 2] = (float)v.z;
  out_vox[t * 4 + 3] = (float)v.w;
  if (t < B) out_nb[t] = (float)numbs[t];
}

// ======================= weight folding (f16, transposed) =======================
// A1[c][k] = M1[k][c]*inv_scale (M1=WqWk^T); A2[c][k] = M2[k][c] (M2=WvWo);
// A3[o][c] = Wout[c][o].
__global__ void prep_all(const float* __restrict__ Wq1, const float* __restrict__ Wk1,
                         const float* __restrict__ Wv1, const float* __restrict__ Wo1,
                         const float* __restrict__ Wout1,
                         const float* __restrict__ Wq2, const float* __restrict__ Wk2,
                         const float* __restrict__ Wv2, const float* __restrict__ Wo2,
                         const float* __restrict__ Wout2,
                         f16* __restrict__ A1a, f16* __restrict__ A2a, f16* __restrict__ A3a,
                         f16* __restrict__ A1b, f16* __restrict__ A2b, f16* __restrict__ A3b) {
  const int idx = blockIdx.x * blockDim.x + threadIdx.x;   // 16384 threads
  if (idx < 4096) {
    const int a = idx >> 6, b = idx & 63;
    float s1 = 0.f, s2 = 0.f;
    for (int c = 0; c < 64; c++) {
      s1 = fmaf(Wq1[b * 64 + c], Wk1[a * 64 + c], s1);
      s2 = fmaf(Wv1[b * 64 + c], Wo1[c * 64 + a], s2);
    }
    A1a[idx] = (f16)(s1 * 0.125f);
    A2a[idx] = (f16)s2;
  }
  if (idx < 8192) {
    const int o = idx >> 6, c = idx & 63;
    A3a[idx] = (f16)Wout1[c * 128 + o];
  }
  {
    const int a = idx >> 7, b = idx & 127;
    float s1 = 0.f, s2 = 0.f;
    for (int c = 0; c < 128; c++) {
      s1 = fmaf(Wq2[b * 128 + c], Wk2[a * 128 + c], s1);
      s2 = fmaf(Wv2[b * 128 + c], Wo2[c * 128 + a], s2);
    }
    A1b[idx] = (f16)(s1 * 0.08838834764831845f);
    A2b[idx] = (f16)s2;
    A3b[idx] = (f16)Wout2[b * 128 + a];
  }
}

// ======================= barrier-free MFMA attention block =====================
// Each wave owns 16 q-rows and runs m1->softmax->m4->m5->m6 independently;
// the ONLY barrier is after the cooperative h/hT build. Fragment-layout
// mismatches (D rows=(lk*4+r) vs A rows=(lane&15)) are resolved through a
// per-wave LDS scratch round-trip (wave-local, in-order DS pipe, no barrier).
__device__ __forceinline__ int swzb(int row) {
  return (((row & 7) ^ (((row >> 3) & 3) << 1)) << 4);
}

template<int ROWLEN>
__device__ __forceinline__ f16x8 ldRow(const f16* b, int row, int k0) {
  return *(const f16x8*)((const char*)b + (((row * ROWLEN + k0) * 2) ^ swzb(row)));
}

// write one D tile column-set into scratch as f16 (rows lk*4+r, col c0+lr)
template<int ROWLEN, bool RELU>
__device__ __forceinline__ void rtWrite(f16* s, int lr, int lk, int c0, f32x4 v) {
  #pragma unroll
  for (int r = 0; r < 4; r++) {
    const int row = lk * 4 + r;
    float x = v[r];
    if (RELU) x = fmaxf(x, 0.f);
    *(f16*)((char*)s + (((row * ROWLEN + c0 + lr) * 2) ^ swzb(row))) = (f16)x;
  }
}

template<int C, bool X16, bool OUT16, int MINW>
__global__ __launch_bounds__(256, MINW) void block_mfma(
    const int* __restrict__ idx_x, const float* __restrict__ ptsP,
    const void* __restrict__ xsrc,
    const float* __restrict__ Wpos, const float* __restrict__ bpos,
    const f16* __restrict__ A1, const f16* __restrict__ A2, const f16* __restrict__ A3,
    void* __restrict__ outp) {
  constexpr int KT = C / 32;       // k-tiles over C
  constexpr int CTL = C / 16;      // col tiles over C
  extern __shared__ char smem[];
  f16* bufH  = (f16*)smem;             // [64][C]  h rows (swizzled)
  f16* bufHT = bufH + 64 * C;          // [C][64]  h^T rows (swizzled)
  f16* scr   = bufHT + 64 * C;         // [4][16][C] per-wave scratch

  const int g = blockIdx.x;
  const int t = threadIdx.x;
  const int lane = t & 63;
  const int w = t >> 6;
  const int lr = lane & 15, lk = lane >> 4;
  const int q = t >> 2, qq = t & 3;
  f16* myS = scr + w * 16 * C;

  // ---- cooperative build: h and hT ----
  {
    const int sx = idx_x[g * 64 + q];
    float xv[C / 4];
    if (X16) {
      #pragma unroll
      for (int i = 0; i < C / 32; i++) {
        f16x8 xr = *(const f16x8*)((const f16*)xsrc + (size_t)sx * C + qq * (C / 4) + i * 8);
        #pragma unroll
        for (int j = 0; j < 8; j++) xv[i * 8 + j] = (float)xr[j];
      }
    } else {
      #pragma unroll
      for (int i = 0; i < C / 16; i++) {
        float4 x0 = *(const float4*)((const float*)xsrc + (size_t)sx * C + qq * (C / 4) + i * 4);
        xv[i * 4 + 0] = x0.x; xv[i * 4 + 1] = x0.y; xv[i * 4 + 2] = x0.z; xv[i * 4 + 3] = x0.w;
      }
    }
    float mx = ptsP[(g * 64 + lane) * 3 + 0];
    float my = ptsP[(g * 64 + lane) * 3 + 1];
    float mz = ptsP[(g * 64 + lane) * 3 + 2];
    #pragma unroll
    for (int o = 32; o > 0; o >>= 1) {
      mx += __shfl_xor(mx, o); my += __shfl_xor(my, o); mz += __shfl_xor(mz, o);
    }
    mx *= (1.f / 64.f); my *= (1.f / 64.f); mz *= (1.f / 64.f);
    const float d0 = ptsP[(g * 64 + q) * 3 + 0] - mx;
    const float d1 = ptsP[(g * 64 + q) * 3 + 1] - my;
    const float d2 = ptsP[(g * 64 + q) * 3 + 2] - mz;
    #pragma unroll
    for (int i = 0; i < C / 32; i++) {
      const int c0 = qq * (C / 4) + i * 8;
      f16x8 hv;
      #pragma unroll
      for (int jj = 0; jj < 8; jj += 4) {
        const float4 w0 = *(const float4*)(Wpos + 0 * C + c0 + jj);
        const float4 w1 = *(const float4*)(Wpos + 1 * C + c0 + jj);
        const float4 w2 = *(const float4*)(Wpos + 2 * C + c0 + jj);
        const float4 bb = *(const float4*)(bpos + c0 + jj);
        hv[jj + 0] = (f16)(xv[i * 8 + jj + 0] * fmaf(d0, w0.x, fmaf(d1, w1.x, fmaf(d2, w2.x, bb.x))));
        hv[jj + 1] = (f16)(xv[i * 8 + jj + 1] * fmaf(d0, w0.y, fmaf(d1, w1.y, fmaf(d2, w2.y, bb.y))));
        hv[jj + 2] = (f16)(xv[i * 8 + jj + 2] * fmaf(d0, w0.z, fmaf(d1, w1.z, fmaf(d2, w2.z, bb.z))));
        hv[jj + 3] = (f16)(xv[i * 8 + jj + 3] * fmaf(d0, w0.w, fmaf(d1, w1.w, fmaf(d2, w2.w, bb.w))));
      }
      *(f16x8*)((char*)bufH + (((q * C + c0) * 2) ^ swzb(q))) = hv;
      #pragma unroll
      for (int jj = 0; jj < 8; jj++)
        *(f16*)((char*)bufHT + ((((c0 + jj) * 64 + q) * 2) ^ swzb(c0 + jj))) = hv[jj];
    }
  }
  __syncthreads();   // the only barrier

  const int qoff = w * 16;

  // ---- m1: t1[q][c] = sum_k h[q][k] M1[k][c]  (B = A1 rows from global) ----
  f16x8 hA[KT];
  #pragma unroll
  for (int kt = 0; kt < KT; kt++) hA[kt] = ldRow<C>(bufH, qoff + lr, kt * 32 + lk * 8);
  {
    f32x4 acc[CTL];
    #pragma unroll
    for (int ct = 0; ct < CTL; ct++) acc[ct] = (f32x4){0.f, 0.f, 0.f, 0.f};
    #pragma unroll
    for (int ct = 0; ct < CTL; ct++)
      #pragma unroll
      for (int kt = 0; kt < KT; kt++) {
        const f16x8 Bw = *(const f16x8*)(A1 + (size_t)(ct * 16 + lr) * C + kt * 32 + lk * 8);
        acc[ct] = __builtin_amdgcn_mfma_f32_16x16x32_f16(hA[kt], Bw, acc[ct], 0, 0, 0);
      }
    #pragma unroll
    for (int ct = 0; ct < CTL; ct++) rtWrite<C, false>(myS, lr, lk, ct * 16, acc[ct]);
  }
  // A-frags of t1
  f16x8 t1f[KT];
  #pragma unroll
  for (int kt = 0; kt < KT; kt++) t1f[kt] = ldRow<C>(myS, lr, kt * 32 + lk * 8);

  // ---- m3: sc[q][j] = sum_c t1[q][c] h[j][c]  (B = h rows from LDS) ----
  f32x4 accS[4];
  #pragma unroll
  for (int jt = 0; jt < 4; jt++) accS[jt] = (f32x4){0.f, 0.f, 0.f, 0.f};
  #pragma unroll
  for (int jt = 0; jt < 4; jt++)
    #pragma unroll
    for (int kt = 0; kt < KT; kt++) {
      const f16x8 Bh = ldRow<C>(bufH, jt * 16 + lr, kt * 32 + lk * 8);
      accS[jt] = __builtin_amdgcn_mfma_f32_16x16x32_f16(t1f[kt], Bh, accS[jt], 0, 0, 0);
    }

  // ---- softmax fully in registers (16-lane shfl groups share a q-row) ----
  {
    float mxv = -3.0e38f;
    #pragma unroll
    for (int jt = 0; jt < 4; jt++)
      #pragma unroll
      for (int r = 0; r < 4; r++) mxv = fmaxf(mxv, accS[jt][r]);
    mxv = fmaxf(mxv, __shfl_xor(mxv, 1));
    mxv = fmaxf(mxv, __shfl_xor(mxv, 2));
    mxv = fmaxf(mxv, __shfl_xor(mxv, 4));
    mxv = fmaxf(mxv, __shfl_xor(mxv, 8));
    float s = 0.f;
    #pragma unroll
    for (int jt = 0; jt < 4; jt++)
      #pragma unroll
      for (int r = 0; r < 4; r++) {
        accS[jt][r] = __expf(accS[jt][r] - mxv);
        s += accS[jt][r];
      }
    s += __shfl_xor(s, 1);
    s += __shfl_xor(s, 2);
    s += __shfl_xor(s, 4);
    s += __shfl_xor(s, 8);
    const float inv = 1.f / s;
    #pragma unroll
    for (int jt = 0; jt < 4; jt++) {
      f32x4 v = accS[jt];
      v[0] *= inv; v[1] *= inv; v[2] *= inv; v[3] *= inv;
      rtWrite<64, false>(myS, lr, lk, jt * 16, v);
    }
  }
  // A-frags of attn
  f16x8 paf[2];
  #pragma unroll
  for (int jt2 = 0; jt2 < 2; jt2++) paf[jt2] = ldRow<64>(myS, lr, jt2 * 32 + lk * 8);

  // ---- m4: t2[q][cv] = sum_j attn[q][j] h[j][cv]  (B = hT rows from LDS) ----
  {
    f32x4 acc[CTL];
    #pragma unroll
    for (int ct = 0; ct < CTL; ct++) acc[ct] = (f32x4){0.f, 0.f, 0.f, 0.f};
    #pragma unroll
    for (int ct = 0; ct < CTL; ct++)
      #pragma unroll
      for (int jt2 = 0; jt2 < 2; jt2++) {
        const f16x8 Bt = ldRow<64>(bufHT, ct * 16 + lr, jt2 * 32 + lk * 8);
        acc[ct] = __builtin_amdgcn_mfma_f32_16x16x32_f16(paf[jt2], Bt, acc[ct], 0, 0, 0);
      }
    #pragma unroll
    for (int ct = 0; ct < CTL; ct++) rtWrite<C, false>(myS, lr, lk, ct * 16, acc[ct]);
  }
  f16x8 t2f[KT];
  #pragma unroll
  for (int kt = 0; kt < KT; kt++) t2f[kt] = ldRow<C>(myS, lr, kt * 32 + lk * 8);

  // ---- m5: o2r[q][c] = relu(sum_cv t2[q][cv] M2[cv][c]) ----
  {
    f32x4 acc[CTL];
    #pragma unroll
    for (int ct = 0; ct < CTL; ct++) acc[ct] = (f32x4){0.f, 0.f, 0.f, 0.f};
    #pragma unroll
    for (int ct = 0; ct < CTL; ct++)
      #pragma unroll
      for (int kt = 0; kt < KT; kt++) {
        const f16x8 Bw = *(const f16x8*)(A2 + (size_t)(ct * 16 + lr) * C + kt * 32 + lk * 8);
        acc[ct] = __builtin_amdgcn_mfma_f32_16x16x32_f16(t2f[kt], Bw, acc[ct], 0, 0, 0);
      }
    #pragma unroll
    for (int ct = 0; ct < CTL; ct++) rtWrite<C, true>(myS, lr, lk, ct * 16, acc[ct]);
  }
  f16x8 of[KT];
  #pragma unroll
  for (int kt = 0; kt < KT; kt++) of[kt] = ldRow<C>(myS, lr, kt * 32 + lk * 8);

  // ---- m6: y[q][o] = sum_c o2r[q][c] Wout[c][o] -> global ----
  {
    f32x4 acc[8];
    #pragma unroll
    for (int ot = 0; ot < 8; ot++) acc[ot] = (f32x4){0.f, 0.f, 0.f, 0.f};
    #pragma unroll
    for (int ot = 0; ot < 8; ot++)
      #pragma unroll
      for (int kt = 0; kt < KT; kt++) {
        const f16x8 Bw = *(const f16x8*)(A3 + (size_t)(ot * 16 + lr) * C + kt * 32 + lk * 8);
        acc[ot] = __builtin_amdgcn_mfma_f32_16x16x32_f16(of[kt], Bw, acc[ot], 0, 0, 0);
      }
    #pragma unroll
    for (int ot = 0; ot < 8; ot++)
      #pragma unroll
      for (int r = 0; r < 4; r++) {
        const size_t row = (size_t)g * 64 + qoff + lk * 4 + r;
        const int col = ot * 16 + lr;
        if (OUT16) ((f16*)outp)[row * 128 + col] = (f16)acc[ot][r];
        else       ((float*)outp)[row * 128 + col] = acc[ot][r];
      }
  }
}

// ======================= host =======================
extern "C" void kernel_launch(void* const* d_in, const int* in_sizes, int n_in,
                              void* d_out, int out_size, void* d_ws, size_t ws_size,
                              hipStream_t stream) {
  const int*   vox_numbs = (const int*)d_in[0];
  const int*   vox_coors = (const int*)d_in[1];
  const float* vox_feats = (const float*)d_in[2];
  const float* pts_coors = (const float*)d_in[3];
  const float* Wpos1 = (const float*)d_in[4];
  const float* bpos1 = (const float*)d_in[5];
  const float* Wq1   = (const float*)d_in[6];
  const float* Wk1   = (const float*)d_in[7];
  const float* Wv1   = (const float*)d_in[8];
  const float* Wo1   = (const float*)d_in[9];
  const float* Wout1 = (const float*)d_in[10];
  const float* Wpos2 = (const float*)d_in[11];
  const float* bpos2 = (const float*)d_in[12];
  const float* Wq2   = (const float*)d_in[13];
  const float* Wk2   = (const float*)d_in[14];
  const float* Wv2   = (const float*)d_in[15];
  const float* Wo2   = (const float*)d_in[16];
  const float* Wout2 = (const float*)d_in[17];

  const int B = in_sizes[0];
  const int n = in_sizes[1] / 4;       // 262144 = 2^18
  const int ngrp = n / 64;

  char* w = (char*)d_ws;
  auto alloc = [&](size_t bytes) {
    char* p = w;
    w += (bytes + 255) & ~(size_t)255;
    return p;
  };
  u64* keys    = (u64*)alloc((size_t)2 * n * 8);   // keys1 | keys2
  int* ind1    = (int*)alloc((size_t)n * 4);
  int* inv1    = (int*)alloc((size_t)n * 4);
  int* g2      = (int*)alloc((size_t)n * 4);
  float* pts1p = (float*)alloc((size_t)n * 3 * 4);
  f16* A1a     = (f16*)alloc(64 * 64 * 2);
  f16* A2a     = (f16*)alloc(64 * 64 * 2);
  f16* A3a     = (f16*)alloc(128 * 64 * 2);
  f16* A1b     = (f16*)alloc(128 * 128 * 2);
  f16* A2b     = (f16*)alloc(128 * 128 * 2);
  f16* A3b     = (f16*)alloc(128 * 128 * 2);
  f16* feats1  = (f16*)alloc((size_t)n * 128 * 2);
  u64* keys2   = keys + n;

  float* out_feats = (float*)d_out;
  float* out_pts   = out_feats + (size_t)n * 128;
  float* out_vox   = out_pts + (size_t)n * 3;
  float* out_nb    = out_vox + (size_t)n * 4;

  auto f64k  = block_mfma<64,  false, true,  4>;
  auto f128k = block_mfma<128, true,  false, 3>;
  hipFuncSetAttribute((const void*)f64k,  hipFuncAttributeMaxDynamicSharedMemorySize, 32768);
  hipFuncSetAttribute((const void*)f128k, hipFuncAttributeMaxDynamicSharedMemorySize, 65536);

  prep_all<<<64, 256, 0, stream>>>(Wq1, Wk1, Wv1, Wo1, Wout1, Wq2, Wk2, Wv2, Wo2, Wout2,
                                   A1a, A2a, A3a, A1b, A2b, A3b);

  // ---- batch-segmented bitonic sort (round-5 measured-best config) ----
  int span = (B > 0) ? n / B : n;
  if (span < 8192 || (span & (span - 1)) != 0 || n % span != 0) span = n;
  const int spanm1 = span - 1;

  sort_tile0<<<2 * n / 4096, 1024, 0, stream>>>(vox_coors, keys, n, spanm1);
  for (int k = 8192; k <= span; k <<= 1) {
    int j = k >> 1;
    while (j >= 4096) {
      int lev = 1;
      while (lev < 4 && (j >> lev) >= 4096) lev++;
      const int jlow = j >> (lev - 1);
      const int nth = (2 * n) >> lev;
      bitonic_gN<<<nth / 256, 256, 0, stream>>>(keys, jlow, lev, k, spanm1);
      j = jlow >> 1;
    }
    merge_tile4<<<2 * n / 4096, 1024, 0, stream>>>(keys, k, spanm1);
  }

  extract_inv_k<<<(n + 255) / 256, 256, 0, stream>>>(keys, pts_coors, ind1, inv1, pts1p, n);
  finish_k<<<(n + 255) / 256, 256, 0, stream>>>(keys2, inv1, g2, pts_coors, vox_coors,
                                                vox_numbs, out_pts, out_vox, out_nb, n, B);

  block_mfma<64, false, true, 4><<<ngrp, 256, 3 * 64 * 64 * 2, stream>>>(
      ind1, pts1p, vox_feats, Wpos1, bpos1, A1a, A2a, A3a, feats1);
  block_mfma<128, true, false, 3><<<ngrp, 256, 3 * 64 * 128 * 2, stream>>>(
      g2, out_pts, feats1, Wpos2, bpos2, A1b, A2b, A3b, out_feats);
}

// Round 10
// 299.469 us; speedup vs baseline: 1.5827x; 1.5827x over previous
//
#include <hip/hip_runtime.h>

using u64 = unsigned long long;
typedef _Float16 f16;
using f16x8 = __attribute__((ext_vector_type(8))) _Float16;
using f16x4 = __attribute__((ext_vector_type(4))) _Float16;
using f32x4 = __attribute__((ext_vector_type(4))) float;

// ======================= Hilbert encode (Skilling) =======================
__device__ __forceinline__ int hilbert3(int X0, int X1, int X2) {
  #pragma unroll
  for (int Q = 256; Q > 1; Q >>= 1) {
    const int P = Q - 1;
    if (X0 & Q) X0 ^= P;
    int t1 = (X0 ^ X1) & P;
    if (X1 & Q) X0 ^= P; else { X0 ^= t1; X1 ^= t1; }
    int t2 = (X0 ^ X2) & P;
    if (X2 & Q) X0 ^= P; else { X0 ^= t2; X2 ^= t2; }
  }
  X1 ^= X0;
  X2 ^= X1;
  int t = 0;
  #pragma unroll
  for (int Q = 256; Q > 1; Q >>= 1) if (X2 & Q) t ^= (Q - 1);
  X0 ^= t; X1 ^= t; X2 ^= t;
  int code = 0;
  #pragma unroll
  for (int b = 8; b >= 0; b--)
    code = (code << 3) | (((X0 >> b) & 1) << 2) | (((X1 >> b) & 1) << 1) | ((X2 >> b) & 1);
  return code;
}

__device__ __forceinline__ void cswap(u64& a, u64& b, bool up) {
  if ((a > b) == up) { u64 t = a; a = b; b = t; }
}

// ======================= batch-segmented bitonic sort (round-5 config) ========
__global__ __launch_bounds__(1024) void sort_tile0(const int* __restrict__ vox,
                                                   u64* __restrict__ keys, int n,
                                                   int spanm1) {
  __shared__ u64 s[4096];
  const int base = blockIdx.x * 4096;
  const int bl = base & spanm1;
  #pragma unroll
  for (int m = 0; m < 4; m++) {
    const int e = base + threadIdx.x + m * 1024;
    const int isrc = e & (n - 1);
    const int4 c = ((const int4*)vox)[isrc];
    const unsigned code = (e < n) ? (unsigned)hilbert3(c.y, c.z, c.w)
                                  : (unsigned)hilbert3(c.w, c.z, c.y);
    s[threadIdx.x + m * 1024] =
        ((u64)(unsigned)c.x << 45) | ((u64)code << 18) | (unsigned)isrc;
  }
  __syncthreads();
  for (int k = 2; k <= 4096; k <<= 1) {
    for (int j = k >> 1; j >= 1; j >>= 1) {
      #pragma unroll
      for (int m = 0; m < 2; m++) {
        const int p = threadIdx.x + m * 1024;
        const int i = ((p & ~(j - 1)) << 1) | (p & (j - 1));
        const bool up = (((bl + i) & k) == 0);
        u64 a = s[i], b = s[i | j];
        if ((a > b) == up) { s[i] = b; s[i | j] = a; }
      }
      __syncthreads();
    }
  }
  #pragma unroll
  for (int m = 0; m < 4; m++)
    keys[base + threadIdx.x + m * 1024] = s[threadIdx.x + m * 1024];
}

template<int LEV>
__device__ __forceinline__ void gstepT(u64* __restrict__ keys, int t, int jlow,
                                       int k, int spanm1) {
  constexpr int S = 1 << LEV;
  const int i0 = ((t & ~(jlow - 1)) << LEV) | (t & (jlow - 1));
  const bool up = (((i0 & spanm1) & k) == 0);
  u64 x[S];
  #pragma unroll
  for (int m = 0; m < S; m++) x[m] = keys[i0 + (size_t)m * jlow];
  #pragma unroll
  for (int d = S >> 1; d >= 1; d >>= 1)
    #pragma unroll
    for (int m = 0; m < S; m++)
      if (!(m & d)) cswap(x[m], x[m | d], up);
  #pragma unroll
  for (int m = 0; m < S; m++) keys[i0 + (size_t)m * jlow] = x[m];
}

__global__ void bitonic_gN(u64* __restrict__ keys, int jlow, int lev, int k, int spanm1) {
  const int t = blockIdx.x * blockDim.x + threadIdx.x;
  switch (lev) {
    case 1: gstepT<1>(keys, t, jlow, k, spanm1); break;
    case 2: gstepT<2>(keys, t, jlow, k, spanm1); break;
    case 3: gstepT<3>(keys, t, jlow, k, spanm1); break;
    default: gstepT<4>(keys, t, jlow, k, spanm1); break;
  }
}

__global__ __launch_bounds__(1024) void merge_tile4(u64* __restrict__ keys, int k,
                                                    int spanm1) {
  __shared__ u64 s[4096];
  const int base = blockIdx.x * 4096;
  #pragma unroll
  for (int m = 0; m < 4; m++)
    s[threadIdx.x + m * 1024] = keys[base + threadIdx.x + m * 1024];
  __syncthreads();
  const bool up = (((base & spanm1) & k) == 0);
  for (int j = 2048; j >= 1; j >>= 1) {
    #pragma unroll
    for (int m = 0; m < 2; m++) {
      const int p = threadIdx.x + m * 1024;
      const int i = ((p & ~(j - 1)) << 1) | (p & (j - 1));
      u64 a = s[i], b = s[i | j];
      if ((a > b) == up) { s[i] = b; s[i | j] = a; }
    }
    __syncthreads();
  }
  #pragma unroll
  for (int m = 0; m < 4; m++)
    keys[base + threadIdx.x + m * 1024] = s[threadIdx.x + m * 1024];
}

// ==== permutation extraction ====
__global__ void extract_inv_k(const u64* __restrict__ keys, const float* __restrict__ pts,
                              int* __restrict__ ind, int* __restrict__ inv,
                              float* __restrict__ pts1p, int n) {
  int t = blockIdx.x * blockDim.x + threadIdx.x;
  if (t >= n) return;
  int s = (int)(keys[t] & 0x3FFFFULL);
  ind[t] = s;
  inv[s] = t;
  pts1p[t * 3 + 0] = pts[s * 3 + 0];
  pts1p[t * 3 + 1] = pts[s * 3 + 1];
  pts1p[t * 3 + 2] = pts[s * 3 + 2];
}

__global__ void finish_k(const u64* __restrict__ keys2, const int* __restrict__ inv1,
                         int* __restrict__ g2, const float* __restrict__ pts,
                         const int* __restrict__ vox, const int* __restrict__ numbs,
                         float* __restrict__ out_pts, float* __restrict__ out_vox,
                         float* __restrict__ out_nb, int n, int B) {
  int t = blockIdx.x * blockDim.x + threadIdx.x;
  if (t >= n) return;
  int s = (int)(keys2[t] & 0x3FFFFULL);
  g2[t] = inv1[s];
  out_pts[t * 3 + 0] = pts[s * 3 + 0];
  out_pts[t * 3 + 1] = pts[s * 3 + 1];
  out_pts[t * 3 + 2] = pts[s * 3 + 2];
  const int4 v = ((const int4*)vox)[s];
  out_vox[t * 4 + 0] = (float)v.x;
  out_vox[t * 4 + 1] = (float)v.y;
  out_vox[t * 4 + 2] = (float)v.z;
  out_vox[t * 4 + 3] = (float)v.w;
  if (t < B) out_nb[t] = (float)numbs[t];
}

// ======================= weight folding (f16, transposed) =======================
__global__ void prep_all(const float* __restrict__ Wq1, const float* __restrict__ Wk1,
                         const float* __restrict__ Wv1, const float* __restrict__ Wo1,
                         const float* __restrict__ Wout1,
                         const float* __restrict__ Wq2, const float* __restrict__ Wk2,
                         const float* __restrict__ Wv2, const float* __restrict__ Wo2,
                         const float* __restrict__ Wout2,
                         f16* __restrict__ A1a, f16* __restrict__ A2a, f16* __restrict__ A3a,
                         f16* __restrict__ A1b, f16* __restrict__ A2b, f16* __restrict__ A3b) {
  const int idx = blockIdx.x * blockDim.x + threadIdx.x;   // 16384 threads
  if (idx < 4096) {
    const int a = idx >> 6, b = idx & 63;
    float s1 = 0.f, s2 = 0.f;
    for (int c = 0; c < 64; c++) {
      s1 = fmaf(Wq1[b * 64 + c], Wk1[a * 64 + c], s1);
      s2 = fmaf(Wv1[b * 64 + c], Wo1[c * 64 + a], s2);
    }
    A1a[idx] = (f16)(s1 * 0.125f);
    A2a[idx] = (f16)s2;
  }
  if (idx < 8192) {
    const int o = idx >> 6, c = idx & 63;
    A3a[idx] = (f16)Wout1[c * 128 + o];
  }
  {
    const int a = idx >> 7, b = idx & 127;
    float s1 = 0.f, s2 = 0.f;
    for (int c = 0; c < 128; c++) {
      s1 = fmaf(Wq2[b * 128 + c], Wk2[a * 128 + c], s1);
      s2 = fmaf(Wv2[b * 128 + c], Wo2[c * 128 + a], s2);
    }
    A1b[idx] = (f16)(s1 * 0.08838834764831845f);
    A2b[idx] = (f16)s2;
    A3b[idx] = (f16)Wout2[b * 128 + a];
  }
}

// ======================= MFMA attention block (round-8 structure) =============
// LDS swizzle: 16B-slot ^= (row&7) ^ (((row>>3)&3)<<1).
__device__ __forceinline__ int swzb(int row) {
  return (((row & 7) ^ (((row >> 3) & 3) << 1)) << 4);
}

template<int M, int K, int AMODE>   // 0=global A[M][K]; 1=LDS rm rows[K]; 2=LDS h^T scalar
__device__ __forceinline__ void gemmT(const f16* __restrict__ Ag, const f16* __restrict__ lA,
                                      const f16* __restrict__ lB, int w, int lane,
                                      f32x4 (&acc)[M / 64][4]) {
  constexpr int CT = M / 64;
  constexpr int KT = K / 32;
  const int lr = lane & 15, lk = lane >> 4;
  if (AMODE == 0) {
    // Stage-local prefetch: ALL weight A-fragments first (32 VGPR transient),
    // then an LDS-only MFMA loop. Keeps global latency off the MFMA chain
    // without cross-stage register liveness (the R5/R6 spill trap).
    f16x8 Af[KT][CT];
    #pragma unroll
    for (int ks = 0; ks < KT; ks++)
      #pragma unroll
      for (int ct = 0; ct < CT; ct++)
        Af[ks][ct] = *(const f16x8*)(Ag + (size_t)(lr + (w * CT + ct) * 16) * K + ks * 32 + lk * 8);
    #pragma unroll
    for (int ks = 0; ks < KT; ks++) {
      const int k0 = ks * 32 + lk * 8;
      f16x8 Bf[4];
      #pragma unroll
      for (int qt = 0; qt < 4; qt++) {
        const int q = lr + qt * 16;
        Bf[qt] = *(const f16x8*)((const char*)lB + (((q * K + k0) * 2) ^ swzb(q)));
      }
      #pragma unroll
      for (int ct = 0; ct < CT; ct++)
        #pragma unroll
        for (int qt = 0; qt < 4; qt++)
          acc[ct][qt] = __builtin_amdgcn_mfma_f32_16x16x32_f16(Af[ks][ct], Bf[qt], acc[ct][qt], 0, 0, 0);
    }
    return;
  }
  #pragma unroll
  for (int ks = 0; ks < KT; ks++) {
    const int k0 = ks * 32 + lk * 8;
    f16x8 Af[CT];
    #pragma unroll
    for (int ct = 0; ct < CT; ct++) {
      const int c = lr + (w * CT + ct) * 16;
      if (AMODE == 1) {
        Af[ct] = *(const f16x8*)((const char*)lA + (((c * K + k0) * 2) ^ swzb(c)));
      } else {
        f16x8 a;
        #pragma unroll
        for (int e = 0; e < 8; e++) {
          const int j = k0 + e;
          a[e] = *(const f16*)((const char*)lA + (((j * M + c) * 2) ^ swzb(j)));
        }
        Af[ct] = a;
      }
    }
    f16x8 Bf[4];
    #pragma unroll
    for (int qt = 0; qt < 4; qt++) {
      const int q = lr + qt * 16;
      Bf[qt] = *(const f16x8*)((const char*)lB + (((q * K + k0) * 2) ^ swzb(q)));
    }
    #pragma unroll
    for (int ct = 0; ct < CT; ct++)
      #pragma unroll
      for (int qt = 0; qt < 4; qt++)
        acc[ct][qt] = __builtin_amdgcn_mfma_f32_16x16x32_f16(Af[ct], Bf[qt], acc[ct][qt], 0, 0, 0);
  }
}

template<int M, bool RELU>
__device__ __forceinline__ void storeT16(f16* __restrict__ dst, int w, int lane,
                                         const f32x4 (&acc)[M / 64][4]) {
  constexpr int CT = M / 64;
  #pragma unroll
  for (int ct = 0; ct < CT; ct++)
    #pragma unroll
    for (int qt = 0; qt < 4; qt++) {
      const int q = (lane & 15) + qt * 16;
      const int c0 = (w * CT + ct) * 16 + (lane >> 4) * 4;
      f16x4 v;
      #pragma unroll
      for (int r = 0; r < 4; r++) {
        float x = acc[ct][qt][r];
        if (RELU) x = fmaxf(x, 0.f);
        v[r] = (f16)x;
      }
      *(f16x4*)((char*)dst + (((q * M + c0) * 2) ^ swzb(q))) = v;
    }
}

template<int C, bool X16, bool OUT16>
__global__ __launch_bounds__(256, 4) void block_mfma(
    const int* __restrict__ idx_x, const float* __restrict__ ptsP,
    const void* __restrict__ xsrc,
    const float* __restrict__ Wpos, const float* __restrict__ bpos,
    const f16* __restrict__ A1, const f16* __restrict__ A2, const f16* __restrict__ A3,
    void* __restrict__ outp) {
  constexpr int CT = C / 64;
  extern __shared__ char smem[];
  f16* bufH = (f16*)smem;            // [64][C] h -> later o2r
  f16* bufT = bufH + 64 * C;         // [64][C] t1 -> later t2
  f16* scH  = bufT + 64 * C;         // [64][64] f16 scores -> attn

  const int g = blockIdx.x;
  const int t = threadIdx.x;
  const int lane = t & 63;
  const int w = t >> 6;
  const int lr = lane & 15, lk = lane >> 4;

  // ---- prefetch A1 fragments (needed right after first barrier) ----
  f16x8 A1f[C / 32][CT];
  #pragma unroll
  for (int ks = 0; ks < C / 32; ks++)
    #pragma unroll
    for (int ct = 0; ct < CT; ct++)
      A1f[ks][ct] = *(const f16x8*)(A1 + (size_t)(lr + (w * CT + ct) * 16) * C + ks * 32 + lk * 8);

  // ---- prefetch gathered x-row piece ----
  const int q = t >> 2, qq = t & 3;
  const int sx = idx_x[g * 64 + q];
  float xv[C / 4];
  if (X16) {
    #pragma unroll
    for (int i = 0; i < C / 32; i++) {
      f16x8 xr = *(const f16x8*)((const f16*)xsrc + (size_t)sx * C + qq * (C / 4) + i * 8);
      #pragma unroll
      for (int j = 0; j < 8; j++) xv[i * 8 + j] = (float)xr[j];
    }
  } else {
    #pragma unroll
    for (int i = 0; i < C / 16; i++) {
      float4 x0 = *(const float4*)((const float*)xsrc + (size_t)sx * C + qq * (C / 4) + i * 4);
      xv[i * 4 + 0] = x0.x; xv[i * 4 + 1] = x0.y; xv[i * 4 + 2] = x0.z; xv[i * 4 + 3] = x0.w;
    }
  }

  // ---- group mean of pts (coalesced; ptsP pre-permuted) ----
  {
    float mx = ptsP[(g * 64 + lane) * 3 + 0];
    float my = ptsP[(g * 64 + lane) * 3 + 1];
    float mz = ptsP[(g * 64 + lane) * 3 + 2];
    #pragma unroll
    for (int o = 32; o > 0; o >>= 1) {
      mx += __shfl_xor(mx, o); my += __shfl_xor(my, o); mz += __shfl_xor(mz, o);
    }
    mx *= (1.f / 64.f); my *= (1.f / 64.f); mz *= (1.f / 64.f);

    const float d0 = ptsP[(g * 64 + q) * 3 + 0] - mx;
    const float d1 = ptsP[(g * 64 + q) * 3 + 1] - my;
    const float d2 = ptsP[(g * 64 + q) * 3 + 2] - mz;
    #pragma unroll
    for (int i = 0; i < C / 32; i++) {
      const int c0 = qq * (C / 4) + i * 8;
      f16x8 hv;
      #pragma unroll
      for (int jj = 0; jj < 8; jj += 4) {
        const float4 w0 = *(const float4*)(Wpos + 0 * C + c0 + jj);
        const float4 w1 = *(const float4*)(Wpos + 1 * C + c0 + jj);
        const float4 w2 = *(const float4*)(Wpos + 2 * C + c0 + jj);
        const float4 bb = *(const float4*)(bpos + c0 + jj);
        hv[jj + 0] = (f16)(xv[i * 8 + jj + 0] * fmaf(d0, w0.x, fmaf(d1, w1.x, fmaf(d2, w2.x, bb.x))));
        hv[jj + 1] = (f16)(xv[i * 8 + jj + 1] * fmaf(d0, w0.y, fmaf(d1, w1.y, fmaf(d2, w2.y, bb.y))));
        hv[jj + 2] = (f16)(xv[i * 8 + jj + 2] * fmaf(d0, w0.z, fmaf(d1, w1.z, fmaf(d2, w2.z, bb.z))));
        hv[jj + 3] = (f16)(xv[i * 8 + jj + 3] * fmaf(d0, w0.w, fmaf(d1, w1.w, fmaf(d2, w2.w, bb.w))));
      }
      *(f16x8*)((char*)bufH + (((q * C + c0) * 2) ^ swzb(q))) = hv;
    }
  }
  __syncthreads();

  // ---- m1: t1^T = A1 @ h^T (A preloaded) -> bufT ----
  {
    f32x4 acc[CT][4] = {};
    #pragma unroll
    for (int ks = 0; ks < C / 32; ks++) {
      const int k0 = ks * 32 + lk * 8;
      f16x8 Bf[4];
      #pragma unroll
      for (int qt = 0; qt < 4; qt++) {
        const int qr = lr + qt * 16;
        Bf[qt] = *(const f16x8*)((const char*)bufH + (((qr * C + k0) * 2) ^ swzb(qr)));
      }
      #pragma unroll
      for (int ct = 0; ct < CT; ct++)
        #pragma unroll
        for (int qt = 0; qt < 4; qt++)
          acc[ct][qt] = __builtin_amdgcn_mfma_f32_16x16x32_f16(A1f[ks][ct], Bf[qt], acc[ct][qt], 0, 0, 0);
    }
    storeT16<C, false>(bufT, w, lane, acc);
  }
  __syncthreads();

  // ---- m3: sc[q][j] -> scH (f16) ----
  {
    f32x4 acc[1][4] = {};
    gemmT<64, C, 1>(nullptr, bufH, bufT, w, lane, acc);
    #pragma unroll
    for (int qt = 0; qt < 4; qt++) {
      const int qr = lr + qt * 16;
      const int j0 = w * 16 + lk * 4;
      f16x4 v;
      #pragma unroll
      for (int r = 0; r < 4; r++) v[r] = (f16)acc[0][qt][r];
      *(f16x4*)((char*)scH + (((qr * 64 + j0) * 2) ^ swzb(qr))) = v;
    }
  }
  __syncthreads();

  // ---- softmax rows of sc (f16 in/out) ----
  {
    float v[16];
    float mxv = -3.0e38f;
    #pragma unroll
    for (int i = 0; i < 2; i++) {
      f16x8 x8 = *(const f16x8*)((const char*)scH + (((q * 64 + qq * 16 + i * 8) * 2) ^ swzb(q)));
      #pragma unroll
      for (int j = 0; j < 8; j++) {
        v[i * 8 + j] = (float)x8[j];
        mxv = fmaxf(mxv, v[i * 8 + j]);
      }
    }
    mxv = fmaxf(mxv, __shfl_xor(mxv, 1));
    mxv = fmaxf(mxv, __shfl_xor(mxv, 2));
    float s = 0.f;
    #pragma unroll
    for (int i = 0; i < 16; i++) { v[i] = __expf(v[i] - mxv); s += v[i]; }
    s += __shfl_xor(s, 1);
    s += __shfl_xor(s, 2);
    const float inv = 1.f / s;
    #pragma unroll
    for (int i = 0; i < 2; i++) {
      f16x8 pk;
      #pragma unroll
      for (int j = 0; j < 8; j++) pk[j] = (f16)(v[i * 8 + j] * inv);
      *(f16x8*)((char*)scH + (((q * 64 + qq * 16 + i * 8) * 2) ^ swzb(q))) = pk;
    }
  }
  __syncthreads();

  // ---- m4: t2^T = h^T @ attn^T -> bufT ----
  {
    f32x4 acc[CT][4] = {};
    gemmT<C, 64, 2>(nullptr, bufH, scH, w, lane, acc);
    storeT16<C, false>(bufT, w, lane, acc);
  }
  __syncthreads();

  // ---- m5: o2r^T = relu(A2 @ t2^T) -> bufH ----
  {
    f32x4 acc[CT][4] = {};
    gemmT<C, C, 0>(A2, nullptr, bufT, w, lane, acc);
    storeT16<C, true>(bufH, w, lane, acc);
  }
  __syncthreads();

  // ---- m6: y^T = A3 @ o2r^T -> global ----
  {
    f32x4 acc[2][4] = {};
    gemmT<128, C, 0>(A3, nullptr, bufH, w, lane, acc);
    #pragma unroll
    for (int ct = 0; ct < 2; ct++)
      #pragma unroll
      for (int qt = 0; qt < 4; qt++) {
        const int qr = (lane & 15) + qt * 16;
        const int o0 = (w * 2 + ct) * 16 + (lane >> 4) * 4;
        const size_t row = (size_t)g * 64 + qr;
        if (OUT16) {
          f16x4 v;
          #pragma unroll
          for (int r = 0; r < 4; r++) v[r] = (f16)acc[ct][qt][r];
          *(f16x4*)((f16*)outp + row * 128 + o0) = v;
        } else {
          *(f32x4*)((float*)outp + row * 128 + o0) = acc[ct][qt];
        }
      }
  }
}

// ======================= host =======================
extern "C" void kernel_launch(void* const* d_in, const int* in_sizes, int n_in,
                              void* d_out, int out_size, void* d_ws, size_t ws_size,
                              hipStream_t stream) {
  const int*   vox_numbs = (const int*)d_in[0];
  const int*   vox_coors = (const int*)d_in[1];
  const float* vox_feats = (const float*)d_in[2];
  const float* pts_coors = (const float*)d_in[3];
  const float* Wpos1 = (const float*)d_in[4];
  const float* bpos1 = (const float*)d_in[5];
  const float* Wq1   = (const float*)d_in[6];
  const float* Wk1   = (const float*)d_in[7];
  const float* Wv1   = (const float*)d_in[8];
  const float* Wo1   = (const float*)d_in[9];
  const float* Wout1 = (const float*)d_in[10];
  const float* Wpos2 = (const float*)d_in[11];
  const float* bpos2 = (const float*)d_in[12];
  const float* Wq2   = (const float*)d_in[13];
  const float* Wk2   = (const float*)d_in[14];
  const float* Wv2   = (const float*)d_in[15];
  const float* Wo2   = (const float*)d_in[16];
  const float* Wout2 = (const float*)d_in[17];

  const int B = in_sizes[0];
  const int n = in_sizes[1] / 4;       // 262144 = 2^18
  const int ngrp = n / 64;

  char* w = (char*)d_ws;
  auto alloc = [&](size_t bytes) {
    char* p = w;
    w += (bytes + 255) & ~(size_t)255;
    return p;
  };
  u64* keys    = (u64*)alloc((size_t)2 * n * 8);   // keys1 | keys2
  int* ind1    = (int*)alloc((size_t)n * 4);
  int* inv1    = (int*)alloc((size_t)n * 4);
  int* g2      = (int*)alloc((size_t)n * 4);
  float* pts1p = (float*)alloc((size_t)n * 3 * 4);
  f16* A1a     = (f16*)alloc(64 * 64 * 2);
  f16* A2a     = (f16*)alloc(64 * 64 * 2);
  f16* A3a     = (f16*)alloc(128 * 64 * 2);
  f16* A1b     = (f16*)alloc(128 * 128 * 2);
  f16* A2b     = (f16*)alloc(128 * 128 * 2);
  f16* A3b     = (f16*)alloc(128 * 128 * 2);
  f16* feats1  = (f16*)alloc((size_t)n * 128 * 2);
  u64* keys2   = keys + n;

  float* out_feats = (float*)d_out;
  float* out_pts   = out_feats + (size_t)n * 128;
  float* out_vox   = out_pts + (size_t)n * 3;
  float* out_nb    = out_vox + (size_t)n * 4;

  auto f64k  = block_mfma<64,  false, true>;
  auto f128k = block_mfma<128, true,  false>;
  hipFuncSetAttribute((const void*)f64k,  hipFuncAttributeMaxDynamicSharedMemorySize, 65536);
  hipFuncSetAttribute((const void*)f128k, hipFuncAttributeMaxDynamicSharedMemorySize, 65536);

  prep_all<<<64, 256, 0, stream>>>(Wq1, Wk1, Wv1, Wo1, Wout1, Wq2, Wk2, Wv2, Wo2, Wout2,
                                   A1a, A2a, A3a, A1b, A2b, A3b);

  // ---- batch-segmented bitonic sort (round-5 measured-best config) ----
  int span = (B > 0) ? n / B : n;
  if (span < 8192 || (span & (span - 1)) != 0 || n % span != 0) span = n;
  const int spanm1 = span - 1;

  sort_tile0<<<2 * n / 4096, 1024, 0, stream>>>(vox_coors, keys, n, spanm1);
  for (int k = 8192; k <= span; k <<= 1) {
    int j = k >> 1;
    while (j >= 4096) {
      int lev = 1;
      while (lev < 4 && (j >> lev) >= 4096) lev++;
      const int jlow = j >> (lev - 1);
      const int nth = (2 * n) >> lev;
      bitonic_gN<<<nth / 256, 256, 0, stream>>>(keys, jlow, lev, k, spanm1);
      j = jlow >> 1;
    }
    merge_tile4<<<2 * n / 4096, 1024, 0, stream>>>(keys, k, spanm1);
  }

  extract_inv_k<<<(n + 255) / 256, 256, 0, stream>>>(keys, pts_coors, ind1, inv1, pts1p, n);
  finish_k<<<(n + 255) / 256, 256, 0, stream>>>(keys2, inv1, g2, pts_coors, vox_coors,
                                                vox_numbs, out_pts, out_vox, out_nb, n, B);

  block_mfma<64, false, true><<<ngrp, 256, 24576, stream>>>(
      ind1, pts1p, vox_feats, Wpos1, bpos1, A1a, A2a, A3a, feats1);
  block_mfma<128, true, false><<<ngrp, 256, 40960, stream>>>(
      g2, out_pts, feats1, Wpos2, bpos2, A1b, A2b, A3b, out_feats);
}

// Round 11
// 273.957 us; speedup vs baseline: 1.7301x; 1.0931x over previous
//
#include <hip/hip_runtime.h>

using u64 = unsigned long long;
typedef _Float16 f16;
using f16x8 = __attribute__((ext_vector_type(8))) _Float16;
using f16x4 = __attribute__((ext_vector_type(4))) _Float16;
using f32x4 = __attribute__((ext_vector_type(4))) float;

// ======================= Hilbert encode (Skilling) =======================
__device__ __forceinline__ int hilbert3(int X0, int X1, int X2) {
  #pragma unroll
  for (int Q = 256; Q > 1; Q >>= 1) {
    const int P = Q - 1;
    if (X0 & Q) X0 ^= P;
    int t1 = (X0 ^ X1) & P;
    if (X1 & Q) X0 ^= P; else { X0 ^= t1; X1 ^= t1; }
    int t2 = (X0 ^ X2) & P;
    if (X2 & Q) X0 ^= P; else { X0 ^= t2; X2 ^= t2; }
  }
  X1 ^= X0;
  X2 ^= X1;
  int t = 0;
  #pragma unroll
  for (int Q = 256; Q > 1; Q >>= 1) if (X2 & Q) t ^= (Q - 1);
  X0 ^= t; X1 ^= t; X2 ^= t;
  int code = 0;
  #pragma unroll
  for (int b = 8; b >= 0; b--)
    code = (code << 3) | (((X0 >> b) & 1) << 2) | (((X1 >> b) & 1) << 1) | ((X2 >> b) & 1);
  return code;
}

__device__ __forceinline__ void cswap(u64& a, u64& b, bool up) {
  if ((a > b) == up) { u64 t = a; a = b; b = t; }
}

// ======================= batch-segmented bitonic sort (round-5 config) ========
__global__ __launch_bounds__(1024) void sort_tile0(const int* __restrict__ vox,
                                                   u64* __restrict__ keys, int n,
                                                   int spanm1) {
  __shared__ u64 s[4096];
  const int base = blockIdx.x * 4096;
  const int bl = base & spanm1;
  #pragma unroll
  for (int m = 0; m < 4; m++) {
    const int e = base + threadIdx.x + m * 1024;
    const int isrc = e & (n - 1);
    const int4 c = ((const int4*)vox)[isrc];
    const unsigned code = (e < n) ? (unsigned)hilbert3(c.y, c.z, c.w)
                                  : (unsigned)hilbert3(c.w, c.z, c.y);
    s[threadIdx.x + m * 1024] =
        ((u64)(unsigned)c.x << 45) | ((u64)code << 18) | (unsigned)isrc;
  }
  __syncthreads();
  for (int k = 2; k <= 4096; k <<= 1) {
    for (int j = k >> 1; j >= 1; j >>= 1) {
      #pragma unroll
      for (int m = 0; m < 2; m++) {
        const int p = threadIdx.x + m * 1024;
        const int i = ((p & ~(j - 1)) << 1) | (p & (j - 1));
        const bool up = (((bl + i) & k) == 0);
        u64 a = s[i], b = s[i | j];
        if ((a > b) == up) { s[i] = b; s[i | j] = a; }
      }
      __syncthreads();
    }
  }
  #pragma unroll
  for (int m = 0; m < 4; m++)
    keys[base + threadIdx.x + m * 1024] = s[threadIdx.x + m * 1024];
}

template<int LEV>
__device__ __forceinline__ void gstepT(u64* __restrict__ keys, int t, int jlow,
                                       int k, int spanm1) {
  constexpr int S = 1 << LEV;
  const int i0 = ((t & ~(jlow - 1)) << LEV) | (t & (jlow - 1));
  const bool up = (((i0 & spanm1) & k) == 0);
  u64 x[S];
  #pragma unroll
  for (int m = 0; m < S; m++) x[m] = keys[i0 + (size_t)m * jlow];
  #pragma unroll
  for (int d = S >> 1; d >= 1; d >>= 1)
    #pragma unroll
    for (int m = 0; m < S; m++)
      if (!(m & d)) cswap(x[m], x[m | d], up);
  #pragma unroll
  for (int m = 0; m < S; m++) keys[i0 + (size_t)m * jlow] = x[m];
}

__global__ void bitonic_gN(u64* __restrict__ keys, int jlow, int lev, int k, int spanm1) {
  const int t = blockIdx.x * blockDim.x + threadIdx.x;
  switch (lev) {
    case 1: gstepT<1>(keys, t, jlow, k, spanm1); break;
    case 2: gstepT<2>(keys, t, jlow, k, spanm1); break;
    case 3: gstepT<3>(keys, t, jlow, k, spanm1); break;
    default: gstepT<4>(keys, t, jlow, k, spanm1); break;
  }
}

__global__ __launch_bounds__(1024) void merge_tile4(u64* __restrict__ keys, int k,
                                                    int spanm1) {
  __shared__ u64 s[4096];
  const int base = blockIdx.x * 4096;
  #pragma unroll
  for (int m = 0; m < 4; m++)
    s[threadIdx.x + m * 1024] = keys[base + threadIdx.x + m * 1024];
  __syncthreads();
  const bool up = (((base & spanm1) & k) == 0);
  for (int j = 2048; j >= 1; j >>= 1) {
    #pragma unroll
    for (int m = 0; m < 2; m++) {
      const int p = threadIdx.x + m * 1024;
      const int i = ((p & ~(j - 1)) << 1) | (p & (j - 1));
      u64 a = s[i], b = s[i | j];
      if ((a > b) == up) { s[i] = b; s[i | j] = a; }
    }
    __syncthreads();
  }
  #pragma unroll
  for (int m = 0; m < 4; m++)
    keys[base + threadIdx.x + m * 1024] = s[threadIdx.x + m * 1024];
}

// ==== permutation extraction ====
__global__ void extract_inv_k(const u64* __restrict__ keys, const float* __restrict__ pts,
                              int* __restrict__ ind, int* __restrict__ inv,
                              float* __restrict__ pts1p, int n) {
  int t = blockIdx.x * blockDim.x + threadIdx.x;
  if (t >= n) return;
  int s = (int)(keys[t] & 0x3FFFFULL);
  ind[t] = s;
  inv[s] = t;
  pts1p[t * 3 + 0] = pts[s * 3 + 0];
  pts1p[t * 3 + 1] = pts[s * 3 + 1];
  pts1p[t * 3 + 2] = pts[s * 3 + 2];
}

__global__ void finish_k(const u64* __restrict__ keys2, const int* __restrict__ inv1,
                         int* __restrict__ g2, const float* __restrict__ pts,
                         const int* __restrict__ vox, const int* __restrict__ numbs,
                         float* __restrict__ out_pts, float* __restrict__ out_vox,
                         float* __restrict__ out_nb, int n, int B) {
  int t = blockIdx.x * blockDim.x + threadIdx.x;
  if (t >= n) return;
  int s = (int)(keys2[t] & 0x3FFFFULL);
  g2[t] = inv1[s];
  out_pts[t * 3 + 0] = pts[s * 3 + 0];
  out_pts[t * 3 + 1] = pts[s * 3 + 1];
  out_pts[t * 3 + 2] = pts[s * 3 + 2];
  const int4 v = ((const int4*)vox)[s];
  out_vox[t * 4 + 0] = (float)v.x;
  out_vox[t * 4 + 1] = (float)v.y;
  out_vox[t * 4 + 2] = (float)v.z;
  out_vox[t * 4 + 3] = (float)v.w;
  if (t < B) out_nb[t] = (float)numbs[t];
}

// ======================= weight folding (f16, transposed) =======================
__global__ void prep_all(const float* __restrict__ Wq1, const float* __restrict__ Wk1,
                         const float* __restrict__ Wv1, const float* __restrict__ Wo1,
                         const float* __restrict__ Wout1,
                         const float* __restrict__ Wq2, const float* __restrict__ Wk2,
                         const float* __restrict__ Wv2, const float* __restrict__ Wo2,
                         const float* __restrict__ Wout2,
                         f16* __restrict__ A1a, f16* __restrict__ A2a, f16* __restrict__ A3a,
                         f16* __restrict__ A1b, f16* __restrict__ A2b, f16* __restrict__ A3b) {
  const int idx = blockIdx.x * blockDim.x + threadIdx.x;   // 16384 threads
  if (idx < 4096) {
    const int a = idx >> 6, b = idx & 63;
    float s1 = 0.f, s2 = 0.f;
    for (int c = 0; c < 64; c++) {
      s1 = fmaf(Wq1[b * 64 + c], Wk1[a * 64 + c], s1);
      s2 = fmaf(Wv1[b * 64 + c], Wo1[c * 64 + a], s2);
    }
    A1a[idx] = (f16)(s1 * 0.125f);
    A2a[idx] = (f16)s2;
  }
  if (idx < 8192) {
    const int o = idx >> 6, c = idx & 63;
    A3a[idx] = (f16)Wout1[c * 128 + o];
  }
  {
    const int a = idx >> 7, b = idx & 127;
    float s1 = 0.f, s2 = 0.f;
    for (int c = 0; c < 128; c++) {
      s1 = fmaf(Wq2[b * 128 + c], Wk2[a * 128 + c], s1);
      s2 = fmaf(Wv2[b * 128 + c], Wo2[c * 128 + a], s2);
    }
    A1b[idx] = (f16)(s1 * 0.08838834764831845f);
    A2b[idx] = (f16)s2;
    A3b[idx] = (f16)Wout2[b * 128 + a];
  }
}

// ======================= MFMA attention block (8-wave fine partition) =========
// Same algorithm/barriers/layouts as the round-8 kernel, but 512 threads per
// group: each wave does HALF the per-phase work (shorter barrier intervals)
// and LDS/block is unchanged -> 4 blocks/CU = 32 waves/CU (100% occupancy)
// so bubbles from synchronized phase stalls are filled by co-resident blocks.
__device__ __forceinline__ int swzb(int row) {
  return (((row & 7) ^ (((row >> 3) & 3) << 1)) << 4);
}

// One GEMM stage tile-set for wave w of 8. Output tiles tau = w*NPW..+NPW-1,
// ct = tau>>2 (uniform in wave), qt = tau&3. AMODE: 0=global A[M][K];
// 1=LDS rows (rowlen K); 2=LDS read as [k][c] (rowlen M, scalar gather).
template<int M, int K, int AMODE>
__device__ __forceinline__ void stage8(const f16* __restrict__ Ag,
                                       const f16* __restrict__ lA,
                                       const f16* __restrict__ lB,
                                       int w, int lane,
                                       f32x4 (&acc)[(M / 16) * 4 / 8]) {
  constexpr int NPW = (M / 16) * 4 / 8;
  constexpr int KT = K / 32;
  const int lr = lane & 15, lk = lane >> 4;
  const int ct = (w * NPW) >> 2;
  const int qt0 = (w * NPW) & 3;
  const int c = ct * 16 + lr;
  f16x8 Af[KT];
  #pragma unroll
  for (int kt = 0; kt < KT; kt++) {
    const int k0 = kt * 32 + lk * 8;
    if (AMODE == 0) {
      Af[kt] = *(const f16x8*)(Ag + (size_t)c * K + k0);
    } else if (AMODE == 1) {
      Af[kt] = *(const f16x8*)((const char*)lA + (((c * K + k0) * 2) ^ swzb(c)));
    } else {
      f16x8 a;
      #pragma unroll
      for (int e = 0; e < 8; e++) {
        const int j = k0 + e;
        a[e] = *(const f16*)((const char*)lA + (((j * M + c) * 2) ^ swzb(j)));
      }
      Af[kt] = a;
    }
  }
  #pragma unroll
  for (int i = 0; i < NPW; i++) {
    const int q = lr + (qt0 + i) * 16;
    #pragma unroll
    for (int kt = 0; kt < KT; kt++) {
      const int k0 = kt * 32 + lk * 8;
      const f16x8 Bf = *(const f16x8*)((const char*)lB + (((q * K + k0) * 2) ^ swzb(q)));
      acc[i] = __builtin_amdgcn_mfma_f32_16x16x32_f16(Af[kt], Bf, acc[i], 0, 0, 0);
    }
  }
}

template<int RL, bool RELU>
__device__ __forceinline__ void store8(f16* __restrict__ dst, int ct, int qt,
                                       int lane, f32x4 v) {
  const int lr = lane & 15, lk = lane >> 4;
  const int q = lr + qt * 16;
  const int c0 = ct * 16 + lk * 4;
  f16x4 o;
  #pragma unroll
  for (int r = 0; r < 4; r++) {
    float x = v[r];
    if (RELU) x = fmaxf(x, 0.f);
    o[r] = (f16)x;
  }
  *(f16x4*)((char*)dst + (((q * RL + c0) * 2) ^ swzb(q))) = o;
}

template<int C, bool X16, bool OUT16>
__global__ __launch_bounds__(512, 8) void block_mfma(
    const int* __restrict__ idx_x, const float* __restrict__ ptsP,
    const void* __restrict__ xsrc,
    const float* __restrict__ Wpos, const float* __restrict__ bpos,
    const f16* __restrict__ A1, const f16* __restrict__ A2, const f16* __restrict__ A3,
    void* __restrict__ outp) {
  constexpr int NPWC = C / 32;             // tiles/wave for M=C stages
  extern __shared__ char smem[];
  f16* bufH = (f16*)smem;            // [64][C] h -> later o2r
  f16* bufT = bufH + 64 * C;         // [64][C] t1 -> later t2
  f16* scH  = bufT + 64 * C;         // [64][64] f16 scores -> attn

  const int g = blockIdx.x;
  const int t = threadIdx.x;
  const int lane = t & 63;
  const int w = t >> 6;
  const int lr = lane & 15, lk = lane >> 4;
  const int q8 = t >> 3, qq = t & 7;       // h-build / softmax: 8 threads per row

  // ---- h = x * ((p-mean)@Wpos + bpos) -> bufH ----
  {
    const int sx = idx_x[g * 64 + q8];
    float mx = ptsP[(g * 64 + lane) * 3 + 0];
    float my = ptsP[(g * 64 + lane) * 3 + 1];
    float mz = ptsP[(g * 64 + lane) * 3 + 2];
    #pragma unroll
    for (int o = 32; o > 0; o >>= 1) {
      mx += __shfl_xor(mx, o); my += __shfl_xor(my, o); mz += __shfl_xor(mz, o);
    }
    mx *= (1.f / 64.f); my *= (1.f / 64.f); mz *= (1.f / 64.f);
    const float d0 = ptsP[(g * 64 + q8) * 3 + 0] - mx;
    const float d1 = ptsP[(g * 64 + q8) * 3 + 1] - my;
    const float d2 = ptsP[(g * 64 + q8) * 3 + 2] - mz;
    #pragma unroll
    for (int i = 0; i < C / 64; i++) {
      const int c0 = qq * (C / 8) + i * 8;
      float xa[8];
      if constexpr (X16) {
        f16x8 xr = *(const f16x8*)((const f16*)xsrc + (size_t)sx * C + c0);
        #pragma unroll
        for (int j = 0; j < 8; j++) xa[j] = (float)xr[j];
      } else {
        float4 x0 = *(const float4*)((const float*)xsrc + (size_t)sx * C + c0);
        float4 x1 = *(const float4*)((const float*)xsrc + (size_t)sx * C + c0 + 4);
        xa[0] = x0.x; xa[1] = x0.y; xa[2] = x0.z; xa[3] = x0.w;
        xa[4] = x1.x; xa[5] = x1.y; xa[6] = x1.z; xa[7] = x1.w;
      }
      f16x8 hv;
      #pragma unroll
      for (int jj = 0; jj < 8; jj += 4) {
        const float4 w0 = *(const float4*)(Wpos + 0 * C + c0 + jj);
        const float4 w1 = *(const float4*)(Wpos + 1 * C + c0 + jj);
        const float4 w2 = *(const float4*)(Wpos + 2 * C + c0 + jj);
        const float4 bb = *(const float4*)(bpos + c0 + jj);
        hv[jj + 0] = (f16)(xa[jj + 0] * fmaf(d0, w0.x, fmaf(d1, w1.x, fmaf(d2, w2.x, bb.x))));
        hv[jj + 1] = (f16)(xa[jj + 1] * fmaf(d0, w0.y, fmaf(d1, w1.y, fmaf(d2, w2.y, bb.y))));
        hv[jj + 2] = (f16)(xa[jj + 2] * fmaf(d0, w0.z, fmaf(d1, w1.z, fmaf(d2, w2.z, bb.z))));
        hv[jj + 3] = (f16)(xa[jj + 3] * fmaf(d0, w0.w, fmaf(d1, w1.w, fmaf(d2, w2.w, bb.w))));
      }
      *(f16x8*)((char*)bufH + (((q8 * C + c0) * 2) ^ swzb(q8))) = hv;
    }
  }
  __syncthreads();

  // ---- m1: t1[q][c] (wave w: 16-col slice ct=w..) -> bufT ----
  {
    f32x4 acc[NPWC] = {};
    stage8<C, C, 0>(A1, nullptr, bufH, w, lane, acc);
    const int ct = (w * NPWC) >> 2, qt0 = (w * NPWC) & 3;
    #pragma unroll
    for (int i = 0; i < NPWC; i++) store8<C, false>(bufT, ct, qt0 + i, lane, acc[i]);
  }
  __syncthreads();

  // ---- m3: sc[q][j] (2 tiles/wave) -> scH ----
  {
    f32x4 acc[2] = {};
    stage8<64, C, 1>(nullptr, bufH, bufT, w, lane, acc);
    const int ct = (w * 2) >> 2, qt0 = (w * 2) & 3;
    #pragma unroll
    for (int i = 0; i < 2; i++) store8<64, false>(scH, ct, qt0 + i, lane, acc[i]);
  }
  __syncthreads();

  // ---- softmax rows of sc (8 threads/row, shfl groups of 8) ----
  {
    f16x8 x8 = *(const f16x8*)((const char*)scH + (((q8 * 64 + qq * 8) * 2) ^ swzb(q8)));
    float v[8];
    float mxv = -3.0e38f;
    #pragma unroll
    for (int j = 0; j < 8; j++) {
      v[j] = (float)x8[j];
      mxv = fmaxf(mxv, v[j]);
    }
    mxv = fmaxf(mxv, __shfl_xor(mxv, 1));
    mxv = fmaxf(mxv, __shfl_xor(mxv, 2));
    mxv = fmaxf(mxv, __shfl_xor(mxv, 4));
    float s = 0.f;
    #pragma unroll
    for (int j = 0; j < 8; j++) { v[j] = __expf(v[j] - mxv); s += v[j]; }
    s += __shfl_xor(s, 1);
    s += __shfl_xor(s, 2);
    s += __shfl_xor(s, 4);
    const float inv = 1.f / s;
    f16x8 pk;
    #pragma unroll
    for (int j = 0; j < 8; j++) pk[j] = (f16)(v[j] * inv);
    *(f16x8*)((char*)scH + (((q8 * 64 + qq * 8) * 2) ^ swzb(q8))) = pk;
  }
  __syncthreads();

  // ---- m4: t2[q][c] = sum_j h[j][c] attn[q][j] -> bufT ----
  {
    f32x4 acc[NPWC] = {};
    stage8<C, 64, 2>(nullptr, bufH, scH, w, lane, acc);
    const int ct = (w * NPWC) >> 2, qt0 = (w * NPWC) & 3;
    #pragma unroll
    for (int i = 0; i < NPWC; i++) store8<C, false>(bufT, ct, qt0 + i, lane, acc[i]);
  }
  __syncthreads();

  // ---- m5: o2r[q][c] = relu(...) -> bufH ----
  {
    f32x4 acc[NPWC] = {};
    stage8<C, C, 0>(A2, nullptr, bufT, w, lane, acc);
    const int ct = (w * NPWC) >> 2, qt0 = (w * NPWC) & 3;
    #pragma unroll
    for (int i = 0; i < NPWC; i++) store8<C, true>(bufH, ct, qt0 + i, lane, acc[i]);
  }
  __syncthreads();

  // ---- m6: y[q][o] -> global (M=128: wave w = 16-col slice ot=w) ----
  {
    f32x4 acc[4] = {};
    stage8<128, C, 0>(A3, nullptr, bufH, w, lane, acc);
    #pragma unroll
    for (int i = 0; i < 4; i++) {
      const int qr = lr + i * 16;
      const int o0 = w * 16 + lk * 4;
      const size_t row = (size_t)g * 64 + qr;
      if (OUT16) {
        f16x4 v;
        #pragma unroll
        for (int r = 0; r < 4; r++) v[r] = (f16)acc[i][r];
        *(f16x4*)((f16*)outp + row * 128 + o0) = v;
      } else {
        *(f32x4*)((float*)outp + row * 128 + o0) = acc[i];
      }
    }
  }
}

// ======================= host =======================
extern "C" void kernel_launch(void* const* d_in, const int* in_sizes, int n_in,
                              void* d_out, int out_size, void* d_ws, size_t ws_size,
                              hipStream_t stream) {
  const int*   vox_numbs = (const int*)d_in[0];
  const int*   vox_coors = (const int*)d_in[1];
  const float* vox_feats = (const float*)d_in[2];
  const float* pts_coors = (const float*)d_in[3];
  const float* Wpos1 = (const float*)d_in[4];
  const float* bpos1 = (const float*)d_in[5];
  const float* Wq1   = (const float*)d_in[6];
  const float* Wk1   = (const float*)d_in[7];
  const float* Wv1   = (const float*)d_in[8];
  const float* Wo1   = (const float*)d_in[9];
  const float* Wout1 = (const float*)d_in[10];
  const float* Wpos2 = (const float*)d_in[11];
  const float* bpos2 = (const float*)d_in[12];
  const float* Wq2   = (const float*)d_in[13];
  const float* Wk2   = (const float*)d_in[14];
  const float* Wv2   = (const float*)d_in[15];
  const float* Wo2   = (const float*)d_in[16];
  const float* Wout2 = (const float*)d_in[17];

  const int B = in_sizes[0];
  const int n = in_sizes[1] / 4;       // 262144 = 2^18
  const int ngrp = n / 64;

  char* w = (char*)d_ws;
  auto alloc = [&](size_t bytes) {
    char* p = w;
    w += (bytes + 255) & ~(size_t)255;
    return p;
  };
  u64* keys    = (u64*)alloc((size_t)2 * n * 8);   // keys1 | keys2
  int* ind1    = (int*)alloc((size_t)n * 4);
  int* inv1    = (int*)alloc((size_t)n * 4);
  int* g2      = (int*)alloc((size_t)n * 4);
  float* pts1p = (float*)alloc((size_t)n * 3 * 4);
  f16* A1a     = (f16*)alloc(64 * 64 * 2);
  f16* A2a     = (f16*)alloc(64 * 64 * 2);
  f16* A3a     = (f16*)alloc(128 * 64 * 2);
  f16* A1b     = (f16*)alloc(128 * 128 * 2);
  f16* A2b     = (f16*)alloc(128 * 128 * 2);
  f16* A3b     = (f16*)alloc(128 * 128 * 2);
  f16* feats1  = (f16*)alloc((size_t)n * 128 * 2);
  u64* keys2   = keys + n;

  float* out_feats = (float*)d_out;
  float* out_pts   = out_feats + (size_t)n * 128;
  float* out_vox   = out_pts + (size_t)n * 3;
  float* out_nb    = out_vox + (size_t)n * 4;

  auto f64k  = block_mfma<64,  false, true>;
  auto f128k = block_mfma<128, true,  false>;
  hipFuncSetAttribute((const void*)f64k,  hipFuncAttributeMaxDynamicSharedMemorySize, 65536);
  hipFuncSetAttribute((const void*)f128k, hipFuncAttributeMaxDynamicSharedMemorySize, 65536);

  prep_all<<<64, 256, 0, stream>>>(Wq1, Wk1, Wv1, Wo1, Wout1, Wq2, Wk2, Wv2, Wo2, Wout2,
                                   A1a, A2a, A3a, A1b, A2b, A3b);

  // ---- batch-segmented bitonic sort (round-5 measured-best config) ----
  int span = (B > 0) ? n / B : n;
  if (span < 8192 || (span & (span - 1)) != 0 || n % span != 0) span = n;
  const int spanm1 = span - 1;

  sort_tile0<<<2 * n / 4096, 1024, 0, stream>>>(vox_coors, keys, n, spanm1);
  for (int k = 8192; k <= span; k <<= 1) {
    int j = k >> 1;
    while (j >= 4096) {
      int lev = 1;
      while (lev < 4 && (j >> lev) >= 4096) lev++;
      const int jlow = j >> (lev - 1);
      const int nth = (2 * n) >> lev;
      bitonic_gN<<<nth / 256, 256, 0, stream>>>(keys, jlow, lev, k, spanm1);
      j = jlow >> 1;
    }
    merge_tile4<<<2 * n / 4096, 1024, 0, stream>>>(keys, k, spanm1);
  }

  extract_inv_k<<<(n + 255) / 256, 256, 0, stream>>>(keys, pts_coors, ind1, inv1, pts1p, n);
  finish_k<<<(n + 255) / 256, 256, 0, stream>>>(keys2, inv1, g2, pts_coors, vox_coors,
                                                vox_numbs, out_pts, out_vox, out_nb, n, B);

  block_mfma<64, false, true><<<ngrp, 512, 24576, stream>>>(
      ind1, pts1p, vox_feats, Wpos1, bpos1, A1a, A2a, A3a, feats1);
  block_mfma<128, true, false><<<ngrp, 512, 40960, stream>>>(
      g2, out_pts, feats1, Wpos2, bpos2, A1b, A2b, A3b, out_feats);
}

// Round 12
// 262.937 us; speedup vs baseline: 1.8027x; 1.0419x over previous
//
#include <hip/hip_runtime.h>

using u64 = unsigned long long;
typedef _Float16 f16;
using f16x8 = __attribute__((ext_vector_type(8))) _Float16;
using f16x4 = __attribute__((ext_vector_type(4))) _Float16;
using f32x4 = __attribute__((ext_vector_type(4))) float;

// ======================= Hilbert encode (Skilling) =======================
__device__ __forceinline__ int hilbert3(int X0, int X1, int X2) {
  #pragma unroll
  for (int Q = 256; Q > 1; Q >>= 1) {
    const int P = Q - 1;
    if (X0 & Q) X0 ^= P;
    int t1 = (X0 ^ X1) & P;
    if (X1 & Q) X0 ^= P; else { X0 ^= t1; X1 ^= t1; }
    int t2 = (X0 ^ X2) & P;
    if (X2 & Q) X0 ^= P; else { X0 ^= t2; X2 ^= t2; }
  }
  X1 ^= X0;
  X2 ^= X1;
  int t = 0;
  #pragma unroll
  for (int Q = 256; Q > 1; Q >>= 1) if (X2 & Q) t ^= (Q - 1);
  X0 ^= t; X1 ^= t; X2 ^= t;
  int code = 0;
  #pragma unroll
  for (int b = 8; b >= 0; b--)
    code = (code << 3) | (((X0 >> b) & 1) << 2) | (((X1 >> b) & 1) << 1) | ((X2 >> b) & 1);
  return code;
}

__device__ __forceinline__ void cswap(u64& a, u64& b, bool up) {
  if ((a > b) == up) { u64 t = a; a = b; b = t; }
}

// ======================= batch-segmented bitonic sort (2048-tiles) ============
// 256 blocks (vs 128 at 4096-tiles) -> 2x CU coverage on tile/merge phases.
__global__ __launch_bounds__(1024) void sort_tile0(const int* __restrict__ vox,
                                                   u64* __restrict__ keys, int n,
                                                   int spanm1) {
  __shared__ u64 s[2048];
  const int base = blockIdx.x * 2048;
  const int bl = base & spanm1;
  #pragma unroll
  for (int m = 0; m < 2; m++) {
    const int e = base + threadIdx.x + m * 1024;
    const int isrc = e & (n - 1);
    const int4 c = ((const int4*)vox)[isrc];
    const unsigned code = (e < n) ? (unsigned)hilbert3(c.y, c.z, c.w)
                                  : (unsigned)hilbert3(c.w, c.z, c.y);
    s[threadIdx.x + m * 1024] =
        ((u64)(unsigned)c.x << 45) | ((u64)code << 18) | (unsigned)isrc;
  }
  __syncthreads();
  for (int k = 2; k <= 2048; k <<= 1) {
    for (int j = k >> 1; j >= 1; j >>= 1) {
      const int p = threadIdx.x;
      const int i = ((p & ~(j - 1)) << 1) | (p & (j - 1));
      const bool up = (((bl + i) & k) == 0);
      u64 a = s[i], b = s[i | j];
      if ((a > b) == up) { s[i] = b; s[i | j] = a; }
      __syncthreads();
    }
  }
  keys[base + threadIdx.x]        = s[threadIdx.x];
  keys[base + threadIdx.x + 1024] = s[threadIdx.x + 1024];
}

template<int LEV>
__device__ __forceinline__ void gstepT(u64* __restrict__ keys, int t, int jlow,
                                       int k, int spanm1) {
  constexpr int S = 1 << LEV;
  const int i0 = ((t & ~(jlow - 1)) << LEV) | (t & (jlow - 1));
  const bool up = (((i0 & spanm1) & k) == 0);
  u64 x[S];
  #pragma unroll
  for (int m = 0; m < S; m++) x[m] = keys[i0 + (size_t)m * jlow];
  #pragma unroll
  for (int d = S >> 1; d >= 1; d >>= 1)
    #pragma unroll
    for (int m = 0; m < S; m++)
      if (!(m & d)) cswap(x[m], x[m | d], up);
  #pragma unroll
  for (int m = 0; m < S; m++) keys[i0 + (size_t)m * jlow] = x[m];
}

__global__ void bitonic_gN(u64* __restrict__ keys, int jlow, int lev, int k, int spanm1) {
  const int t = blockIdx.x * blockDim.x + threadIdx.x;
  switch (lev) {
    case 1: gstepT<1>(keys, t, jlow, k, spanm1); break;
    case 2: gstepT<2>(keys, t, jlow, k, spanm1); break;
    case 3: gstepT<3>(keys, t, jlow, k, spanm1); break;
    default: gstepT<4>(keys, t, jlow, k, spanm1); break;
  }
}

__global__ __launch_bounds__(1024) void merge_tile2(u64* __restrict__ keys, int k,
                                                    int spanm1) {
  __shared__ u64 s[2048];
  const int base = blockIdx.x * 2048;
  s[threadIdx.x]        = keys[base + threadIdx.x];
  s[threadIdx.x + 1024] = keys[base + threadIdx.x + 1024];
  __syncthreads();
  const bool up = (((base & spanm1) & k) == 0);  // k >= 4096 > tile => uniform
  for (int j = 1024; j >= 1; j >>= 1) {
    const int p = threadIdx.x;
    const int i = ((p & ~(j - 1)) << 1) | (p & (j - 1));
    u64 a = s[i], b = s[i | j];
    if ((a > b) == up) { s[i] = b; s[i | j] = a; }
    __syncthreads();
  }
  keys[base + threadIdx.x]        = s[threadIdx.x];
  keys[base + threadIdx.x + 1024] = s[threadIdx.x + 1024];
}

// ==== permutation extraction ====
__global__ void extract_inv_k(const u64* __restrict__ keys, const float* __restrict__ pts,
                              int* __restrict__ ind, int* __restrict__ inv,
                              float* __restrict__ pts1p, int n) {
  int t = blockIdx.x * blockDim.x + threadIdx.x;
  if (t >= n) return;
  int s = (int)(keys[t] & 0x3FFFFULL);
  ind[t] = s;
  inv[s] = t;
  pts1p[t * 3 + 0] = pts[s * 3 + 0];
  pts1p[t * 3 + 1] = pts[s * 3 + 1];
  pts1p[t * 3 + 2] = pts[s * 3 + 2];
}

__global__ void finish_k(const u64* __restrict__ keys2, const int* __restrict__ inv1,
                         int* __restrict__ g2, const float* __restrict__ pts,
                         const int* __restrict__ vox, const int* __restrict__ numbs,
                         float* __restrict__ out_pts, float* __restrict__ out_vox,
                         float* __restrict__ out_nb, int n, int B) {
  int t = blockIdx.x * blockDim.x + threadIdx.x;
  if (t >= n) return;
  int s = (int)(keys2[t] & 0x3FFFFULL);
  g2[t] = inv1[s];
  out_pts[t * 3 + 0] = pts[s * 3 + 0];
  out_pts[t * 3 + 1] = pts[s * 3 + 1];
  out_pts[t * 3 + 2] = pts[s * 3 + 2];
  const int4 v = ((const int4*)vox)[s];
  out_vox[t * 4 + 0] = (float)v.x;
  out_vox[t * 4 + 1] = (float)v.y;
  out_vox[t * 4 + 2] = (float)v.z;
  out_vox[t * 4 + 3] = (float)v.w;
  if (t < B) out_nb[t] = (float)numbs[t];
}

// ======================= weight folding (f16, transposed) =======================
__global__ void prep_all(const float* __restrict__ Wq1, const float* __restrict__ Wk1,
                         const float* __restrict__ Wv1, const float* __restrict__ Wo1,
                         const float* __restrict__ Wout1,
                         const float* __restrict__ Wq2, const float* __restrict__ Wk2,
                         const float* __restrict__ Wv2, const float* __restrict__ Wo2,
                         const float* __restrict__ Wout2,
                         f16* __restrict__ A1a, f16* __restrict__ A2a, f16* __restrict__ A3a,
                         f16* __restrict__ A1b, f16* __restrict__ A2b, f16* __restrict__ A3b) {
  const int idx = blockIdx.x * blockDim.x + threadIdx.x;   // 16384 threads
  if (idx < 4096) {
    const int a = idx >> 6, b = idx & 63;
    float s1 = 0.f, s2 = 0.f;
    for (int c = 0; c < 64; c++) {
      s1 = fmaf(Wq1[b * 64 + c], Wk1[a * 64 + c], s1);
      s2 = fmaf(Wv1[b * 64 + c], Wo1[c * 64 + a], s2);
    }
    A1a[idx] = (f16)(s1 * 0.125f);
    A2a[idx] = (f16)s2;
  }
  if (idx < 8192) {
    const int o = idx >> 6, c = idx & 63;
    A3a[idx] = (f16)Wout1[c * 128 + o];
  }
  {
    const int a = idx >> 7, b = idx & 127;
    float s1 = 0.f, s2 = 0.f;
    for (int c = 0; c < 128; c++) {
      s1 = fmaf(Wq2[b * 128 + c], Wk2[a * 128 + c], s1);
      s2 = fmaf(Wv2[b * 128 + c], Wo2[c * 128 + a], s2);
    }
    A1b[idx] = (f16)(s1 * 0.08838834764831845f);
    A2b[idx] = (f16)s2;
    A3b[idx] = (f16)Wout2[b * 128 + a];
  }
}

// ======================= MFMA attention block (8-wave fine partition) =========
__device__ __forceinline__ int swzb(int row) {
  return (((row & 7) ^ (((row >> 3) & 3) << 1)) << 4);
}

template<int M, int K, int AMODE>
__device__ __forceinline__ void stage8(const f16* __restrict__ Ag,
                                       const f16* __restrict__ lA,
                                       const f16* __restrict__ lB,
                                       int w, int lane,
                                       f32x4 (&acc)[(M / 16) * 4 / 8]) {
  constexpr int NPW = (M / 16) * 4 / 8;
  constexpr int KT = K / 32;
  const int lr = lane & 15, lk = lane >> 4;
  const int ct = (w * NPW) >> 2;
  const int qt0 = (w * NPW) & 3;
  const int c = ct * 16 + lr;
  f16x8 Af[KT];
  #pragma unroll
  for (int kt = 0; kt < KT; kt++) {
    const int k0 = kt * 32 + lk * 8;
    if (AMODE == 0) {
      Af[kt] = *(const f16x8*)(Ag + (size_t)c * K + k0);
    } else if (AMODE == 1) {
      Af[kt] = *(const f16x8*)((const char*)lA + (((c * K + k0) * 2) ^ swzb(c)));
    } else {
      f16x8 a;
      #pragma unroll
      for (int e = 0; e < 8; e++) {
        const int j = k0 + e;
        a[e] = *(const f16*)((const char*)lA + (((j * M + c) * 2) ^ swzb(j)));
      }
      Af[kt] = a;
    }
  }
  __builtin_amdgcn_s_setprio(1);
  #pragma unroll
  for (int i = 0; i < NPW; i++) {
    const int q = lr + (qt0 + i) * 16;
    #pragma unroll
    for (int kt = 0; kt < KT; kt++) {
      const int k0 = kt * 32 + lk * 8;
      const f16x8 Bf = *(const f16x8*)((const char*)lB + (((q * K + k0) * 2) ^ swzb(q)));
      acc[i] = __builtin_amdgcn_mfma_f32_16x16x32_f16(Af[kt], Bf, acc[i], 0, 0, 0);
    }
  }
  __builtin_amdgcn_s_setprio(0);
}

template<int RL, bool RELU>
__device__ __forceinline__ void store8(f16* __restrict__ dst, int ct, int qt,
                                       int lane, f32x4 v) {
  const int lr = lane & 15, lk = lane >> 4;
  const int q = lr + qt * 16;
  const int c0 = ct * 16 + lk * 4;
  f16x4 o;
  #pragma unroll
  for (int r = 0; r < 4; r++) {
    float x = v[r];
    if (RELU) x = fmaxf(x, 0.f);
    o[r] = (f16)x;
  }
  *(f16x4*)((char*)dst + (((q * RL + c0) * 2) ^ swzb(q))) = o;
}

template<int C, bool X16, bool OUT16>
__global__ __launch_bounds__(512, 8) void block_mfma(
    const int* __restrict__ idx_x, const float* __restrict__ ptsP,
    const void* __restrict__ xsrc,
    const float* __restrict__ Wpos, const float* __restrict__ bpos,
    const f16* __restrict__ A1, const f16* __restrict__ A2, const f16* __restrict__ A3,
    void* __restrict__ outp) {
  constexpr int NPWC = C / 32;             // tiles/wave for M=C stages
  extern __shared__ char smem[];
  f16* bufH = (f16*)smem;            // [64][C] h -> later o2r
  f16* bufT = bufH + 64 * C;         // [64][C] t1 -> later t2
  f16* scH  = bufT + 64 * C;         // [64][64] f16 scores -> attn

  const int g = blockIdx.x;
  const int t = threadIdx.x;
  const int lane = t & 63;
  const int w = t >> 6;
  const int lr = lane & 15, lk = lane >> 4;
  const int q8 = t >> 3, qq = t & 7;       // h-build / softmax: 8 threads per row

  // ---- h = x * ((p-mean)@Wpos + bpos) -> bufH ----
  {
    const int sx = idx_x[g * 64 + q8];
    float mx = ptsP[(g * 64 + lane) * 3 + 0];
    float my = ptsP[(g * 64 + lane) * 3 + 1];
    float mz = ptsP[(g * 64 + lane) * 3 + 2];
    #pragma unroll
    for (int o = 32; o > 0; o >>= 1) {
      mx += __shfl_xor(mx, o); my += __shfl_xor(my, o); mz += __shfl_xor(mz, o);
    }
    mx *= (1.f / 64.f); my *= (1.f / 64.f); mz *= (1.f / 64.f);
    const float d0 = ptsP[(g * 64 + q8) * 3 + 0] - mx;
    const float d1 = ptsP[(g * 64 + q8) * 3 + 1] - my;
    const float d2 = ptsP[(g * 64 + q8) * 3 + 2] - mz;
    #pragma unroll
    for (int i = 0; i < C / 64; i++) {
      const int c0 = qq * (C / 8) + i * 8;
      float xa[8];
      if constexpr (X16) {
        f16x8 xr = *(const f16x8*)((const f16*)xsrc + (size_t)sx * C + c0);
        #pragma unroll
        for (int j = 0; j < 8; j++) xa[j] = (float)xr[j];
      } else {
        float4 x0 = *(const float4*)((const float*)xsrc + (size_t)sx * C + c0);
        float4 x1 = *(const float4*)((const float*)xsrc + (size_t)sx * C + c0 + 4);
        xa[0] = x0.x; xa[1] = x0.y; xa[2] = x0.z; xa[3] = x0.w;
        xa[4] = x1.x; xa[5] = x1.y; xa[6] = x1.z; xa[7] = x1.w;
      }
      f16x8 hv;
      #pragma unroll
      for (int jj = 0; jj < 8; jj += 4) {
        const float4 w0 = *(const float4*)(Wpos + 0 * C + c0 + jj);
        const float4 w1 = *(const float4*)(Wpos + 1 * C + c0 + jj);
        const float4 w2 = *(const float4*)(Wpos + 2 * C + c0 + jj);
        const float4 bb = *(const float4*)(bpos + c0 + jj);
        hv[jj + 0] = (f16)(xa[jj + 0] * fmaf(d0, w0.x, fmaf(d1, w1.x, fmaf(d2, w2.x, bb.x))));
        hv[jj + 1] = (f16)(xa[jj + 1] * fmaf(d0, w0.y, fmaf(d1, w1.y, fmaf(d2, w2.y, bb.y))));
        hv[jj + 2] = (f16)(xa[jj + 2] * fmaf(d0, w0.z, fmaf(d1, w1.z, fmaf(d2, w2.z, bb.z))));
        hv[jj + 3] = (f16)(xa[jj + 3] * fmaf(d0, w0.w, fmaf(d1, w1.w, fmaf(d2, w2.w, bb.w))));
      }
      *(f16x8*)((char*)bufH + (((q8 * C + c0) * 2) ^ swzb(q8))) = hv;
    }
  }
  __syncthreads();

  // ---- m1: t1[q][c] (wave w: 16-col slice) -> bufT ----
  {
    f32x4 acc[NPWC] = {};
    stage8<C, C, 0>(A1, nullptr, bufH, w, lane, acc);
    const int ct = (w * NPWC) >> 2, qt0 = (w * NPWC) & 3;
    #pragma unroll
    for (int i = 0; i < NPWC; i++) store8<C, false>(bufT, ct, qt0 + i, lane, acc[i]);
  }
  __syncthreads();

  // ---- m3: sc[q][j] (2 tiles/wave) -> scH ----
  {
    f32x4 acc[2] = {};
    stage8<64, C, 1>(nullptr, bufH, bufT, w, lane, acc);
    const int ct = (w * 2) >> 2, qt0 = (w * 2) & 3;
    #pragma unroll
    for (int i = 0; i < 2; i++) store8<64, false>(scH, ct, qt0 + i, lane, acc[i]);
  }
  __syncthreads();

  // ---- softmax rows of sc (8 threads/row, shfl groups of 8) ----
  {
    f16x8 x8 = *(const f16x8*)((const char*)scH + (((q8 * 64 + qq * 8) * 2) ^ swzb(q8)));
    float v[8];
    float mxv = -3.0e38f;
    #pragma unroll
    for (int j = 0; j < 8; j++) {
      v[j] = (float)x8[j];
      mxv = fmaxf(mxv, v[j]);
    }
    mxv = fmaxf(mxv, __shfl_xor(mxv, 1));
    mxv = fmaxf(mxv, __shfl_xor(mxv, 2));
    mxv = fmaxf(mxv, __shfl_xor(mxv, 4));
    float s = 0.f;
    #pragma unroll
    for (int j = 0; j < 8; j++) { v[j] = __expf(v[j] - mxv); s += v[j]; }
    s += __shfl_xor(s, 1);
    s += __shfl_xor(s, 2);
    s += __shfl_xor(s, 4);
    const float inv = 1.f / s;
    f16x8 pk;
    #pragma unroll
    for (int j = 0; j < 8; j++) pk[j] = (f16)(v[j] * inv);
    *(f16x8*)((char*)scH + (((q8 * 64 + qq * 8) * 2) ^ swzb(q8))) = pk;
  }
  __syncthreads();

  // ---- m4: t2[q][c] = sum_j h[j][c] attn[q][j] -> bufT ----
  {
    f32x4 acc[NPWC] = {};
    stage8<C, 64, 2>(nullptr, bufH, scH, w, lane, acc);
    const int ct = (w * NPWC) >> 2, qt0 = (w * NPWC) & 3;
    #pragma unroll
    for (int i = 0; i < NPWC; i++) store8<C, false>(bufT, ct, qt0 + i, lane, acc[i]);
  }
  __syncthreads();

  // ---- m5: o2r[q][c] = relu(...) -> bufH ----
  {
    f32x4 acc[NPWC] = {};
    stage8<C, C, 0>(A2, nullptr, bufT, w, lane, acc);
    const int ct = (w * NPWC) >> 2, qt0 = (w * NPWC) & 3;
    #pragma unroll
    for (int i = 0; i < NPWC; i++) store8<C, true>(bufH, ct, qt0 + i, lane, acc[i]);
  }
  __syncthreads();

  // ---- m6: y[q][o] -> global (M=128: wave w = 16-col slice ot=w) ----
  {
    f32x4 acc[4] = {};
    stage8<128, C, 0>(A3, nullptr, bufH, w, lane, acc);
    #pragma unroll
    for (int i = 0; i < 4; i++) {
      const int qr = lr + i * 16;
      const int o0 = w * 16 + lk * 4;
      const size_t row = (size_t)g * 64 + qr;
      if (OUT16) {
        f16x4 v;
        #pragma unroll
        for (int r = 0; r < 4; r++) v[r] = (f16)acc[i][r];
        *(f16x4*)((f16*)outp + row * 128 + o0) = v;
      } else {
        *(f32x4*)((float*)outp + row * 128 + o0) = acc[i];
      }
    }
  }
}

// ======================= host =======================
extern "C" void kernel_launch(void* const* d_in, const int* in_sizes, int n_in,
                              void* d_out, int out_size, void* d_ws, size_t ws_size,
                              hipStream_t stream) {
  const int*   vox_numbs = (const int*)d_in[0];
  const int*   vox_coors = (const int*)d_in[1];
  const float* vox_feats = (const float*)d_in[2];
  const float* pts_coors = (const float*)d_in[3];
  const float* Wpos1 = (const float*)d_in[4];
  const float* bpos1 = (const float*)d_in[5];
  const float* Wq1   = (const float*)d_in[6];
  const float* Wk1   = (const float*)d_in[7];
  const float* Wv1   = (const float*)d_in[8];
  const float* Wo1   = (const float*)d_in[9];
  const float* Wout1 = (const float*)d_in[10];
  const float* Wpos2 = (const float*)d_in[11];
  const float* bpos2 = (const float*)d_in[12];
  const float* Wq2   = (const float*)d_in[13];
  const float* Wk2   = (const float*)d_in[14];
  const float* Wv2   = (const float*)d_in[15];
  const float* Wo2   = (const float*)d_in[16];
  const float* Wout2 = (const float*)d_in[17];

  const int B = in_sizes[0];
  const int n = in_sizes[1] / 4;       // 262144 = 2^18
  const int ngrp = n / 64;

  char* w = (char*)d_ws;
  auto alloc = [&](size_t bytes) {
    char* p = w;
    w += (bytes + 255) & ~(size_t)255;
    return p;
  };
  u64* keys    = (u64*)alloc((size_t)2 * n * 8);   // keys1 | keys2
  int* ind1    = (int*)alloc((size_t)n * 4);
  int* inv1    = (int*)alloc((size_t)n * 4);
  int* g2      = (int*)alloc((size_t)n * 4);
  float* pts1p = (float*)alloc((size_t)n * 3 * 4);
  f16* A1a     = (f16*)alloc(64 * 64 * 2);
  f16* A2a     = (f16*)alloc(64 * 64 * 2);
  f16* A3a     = (f16*)alloc(128 * 64 * 2);
  f16* A1b     = (f16*)alloc(128 * 128 * 2);
  f16* A2b     = (f16*)alloc(128 * 128 * 2);
  f16* A3b     = (f16*)alloc(128 * 128 * 2);
  f16* feats1  = (f16*)alloc((size_t)n * 128 * 2);
  u64* keys2   = keys + n;

  float* out_feats = (float*)d_out;
  float* out_pts   = out_feats + (size_t)n * 128;
  float* out_vox   = out_pts + (size_t)n * 3;
  float* out_nb    = out_vox + (size_t)n * 4;

  auto f64k  = block_mfma<64,  false, true>;
  auto f128k = block_mfma<128, true,  false>;
  hipFuncSetAttribute((const void*)f64k,  hipFuncAttributeMaxDynamicSharedMemorySize, 65536);
  hipFuncSetAttribute((const void*)f128k, hipFuncAttributeMaxDynamicSharedMemorySize, 65536);

  prep_all<<<64, 256, 0, stream>>>(Wq1, Wk1, Wv1, Wo1, Wout1, Wq2, Wk2, Wv2, Wo2, Wout2,
                                   A1a, A2a, A3a, A1b, A2b, A3b);

  // ---- batch-segmented bitonic sort (2048-tiles, both orderings) ----
  int span = (B > 0) ? n / B : n;
  if (span < 4096 || (span & (span - 1)) != 0 || n % span != 0) span = n;
  const int spanm1 = span - 1;

  sort_tile0<<<2 * n / 2048, 1024, 0, stream>>>(vox_coors, keys, n, spanm1);
  for (int k = 4096; k <= span; k <<= 1) {
    int j = k >> 1;
    while (j >= 2048) {
      int lev = 1;
      while (lev < 4 && (j >> lev) >= 2048) lev++;
      const int jlow = j >> (lev - 1);
      const int nth = (2 * n) >> lev;
      bitonic_gN<<<nth / 256, 256, 0, stream>>>(keys, jlow, lev, k, spanm1);
      j = jlow >> 1;
    }
    merge_tile2<<<2 * n / 2048, 1024, 0, stream>>>(keys, k, spanm1);
  }

  extract_inv_k<<<(n + 255) / 256, 256, 0, stream>>>(keys, pts_coors, ind1, inv1, pts1p, n);
  finish_k<<<(n + 255) / 256, 256, 0, stream>>>(keys2, inv1, g2, pts_coors, vox_coors,
                                                vox_numbs, out_pts, out_vox, out_nb, n, B);

  block_mfma<64, false, true><<<ngrp, 512, 24576, stream>>>(
      ind1, pts1p, vox_feats, Wpos1, bpos1, A1a, A2a, A3a, feats1);
  block_mfma<128, true, false><<<ngrp, 512, 40960, stream>>>(
      g2, out_pts, feats1, Wpos2, bpos2, A1b, A2b, A3b, out_feats);
}

// Round 13
// 260.786 us; speedup vs baseline: 1.8175x; 1.0082x over previous
//
#include <hip/hip_runtime.h>

using u64 = unsigned long long;
typedef _Float16 f16;
using f16x8 = __attribute__((ext_vector_type(8))) _Float16;
using f16x4 = __attribute__((ext_vector_type(4))) _Float16;
using f32x4 = __attribute__((ext_vector_type(4))) float;

// ======================= Hilbert encode (Skilling) =======================
__device__ __forceinline__ int hilbert3(int X0, int X1, int X2) {
  #pragma unroll
  for (int Q = 256; Q > 1; Q >>= 1) {
    const int P = Q - 1;
    if (X0 & Q) X0 ^= P;
    int t1 = (X0 ^ X1) & P;
    if (X1 & Q) X0 ^= P; else { X0 ^= t1; X1 ^= t1; }
    int t2 = (X0 ^ X2) & P;
    if (X2 & Q) X0 ^= P; else { X0 ^= t2; X2 ^= t2; }
  }
  X1 ^= X0;
  X2 ^= X1;
  int t = 0;
  #pragma unroll
  for (int Q = 256; Q > 1; Q >>= 1) if (X2 & Q) t ^= (Q - 1);
  X0 ^= t; X1 ^= t; X2 ^= t;
  int code = 0;
  #pragma unroll
  for (int b = 8; b >= 0; b--)
    code = (code << 3) | (((X0 >> b) & 1) << 2) | (((X1 >> b) & 1) << 1) | ((X2 >> b) & 1);
  return code;
}

__device__ __forceinline__ void cswap(u64& a, u64& b, bool up) {
  if ((a > b) == up) { u64 t = a; a = b; b = t; }
}

// ======================= batch-segmented bitonic sort (2048-tiles) ============
__global__ __launch_bounds__(1024) void sort_tile0(const int* __restrict__ vox,
                                                   u64* __restrict__ keys, int n,
                                                   int spanm1) {
  __shared__ u64 s[2048];
  const int base = blockIdx.x * 2048;
  const int bl = base & spanm1;
  #pragma unroll
  for (int m = 0; m < 2; m++) {
    const int e = base + threadIdx.x + m * 1024;
    const int isrc = e & (n - 1);
    const int4 c = ((const int4*)vox)[isrc];
    const unsigned code = (e < n) ? (unsigned)hilbert3(c.y, c.z, c.w)
                                  : (unsigned)hilbert3(c.w, c.z, c.y);
    s[threadIdx.x + m * 1024] =
        ((u64)(unsigned)c.x << 45) | ((u64)code << 18) | (unsigned)isrc;
  }
  __syncthreads();
  for (int k = 2; k <= 2048; k <<= 1) {
    for (int j = k >> 1; j >= 1; j >>= 1) {
      const int p = threadIdx.x;
      const int i = ((p & ~(j - 1)) << 1) | (p & (j - 1));
      const bool up = (((bl + i) & k) == 0);
      u64 a = s[i], b = s[i | j];
      if ((a > b) == up) { s[i] = b; s[i | j] = a; }
      __syncthreads();
    }
  }
  keys[base + threadIdx.x]        = s[threadIdx.x];
  keys[base + threadIdx.x + 1024] = s[threadIdx.x + 1024];
}

template<int LEV>
__device__ __forceinline__ void gstepT(u64* __restrict__ keys, int t, int jlow,
                                       int k, int spanm1) {
  constexpr int S = 1 << LEV;
  const int i0 = ((t & ~(jlow - 1)) << LEV) | (t & (jlow - 1));
  const bool up = (((i0 & spanm1) & k) == 0);
  u64 x[S];
  #pragma unroll
  for (int m = 0; m < S; m++) x[m] = keys[i0 + (size_t)m * jlow];
  #pragma unroll
  for (int d = S >> 1; d >= 1; d >>= 1)
    #pragma unroll
    for (int m = 0; m < S; m++)
      if (!(m & d)) cswap(x[m], x[m | d], up);
  #pragma unroll
  for (int m = 0; m < S; m++) keys[i0 + (size_t)m * jlow] = x[m];
}

__global__ void bitonic_gN(u64* __restrict__ keys, int jlow, int lev, int k, int spanm1) {
  const int t = blockIdx.x * blockDim.x + threadIdx.x;
  switch (lev) {
    case 1: gstepT<1>(keys, t, jlow, k, spanm1); break;
    case 2: gstepT<2>(keys, t, jlow, k, spanm1); break;
    case 3: gstepT<3>(keys, t, jlow, k, spanm1); break;
    default: gstepT<4>(keys, t, jlow, k, spanm1); break;
  }
}

__global__ __launch_bounds__(1024) void merge_tile2(u64* __restrict__ keys, int k,
                                                    int spanm1) {
  __shared__ u64 s[2048];
  const int base = blockIdx.x * 2048;
  s[threadIdx.x]        = keys[base + threadIdx.x];
  s[threadIdx.x + 1024] = keys[base + threadIdx.x + 1024];
  __syncthreads();
  const bool up = (((base & spanm1) & k) == 0);  // k >= 4096 > tile => uniform
  for (int j = 1024; j >= 1; j >>= 1) {
    const int p = threadIdx.x;
    const int i = ((p & ~(j - 1)) << 1) | (p & (j - 1));
    u64 a = s[i], b = s[i | j];
    if ((a > b) == up) { s[i] = b; s[i | j] = a; }
    __syncthreads();
  }
  keys[base + threadIdx.x]        = s[threadIdx.x];
  keys[base + threadIdx.x + 1024] = s[threadIdx.x + 1024];
}

// ==== permutation extraction ====
__global__ void extract_inv_k(const u64* __restrict__ keys, const float* __restrict__ pts,
                              int* __restrict__ ind, int* __restrict__ inv,
                              float* __restrict__ pts1p, int n) {
  int t = blockIdx.x * blockDim.x + threadIdx.x;
  if (t >= n) return;
  int s = (int)(keys[t] & 0x3FFFFULL);
  ind[t] = s;
  inv[s] = t;
  pts1p[t * 3 + 0] = pts[s * 3 + 0];
  pts1p[t * 3 + 1] = pts[s * 3 + 1];
  pts1p[t * 3 + 2] = pts[s * 3 + 2];
}

__global__ void finish_k(const u64* __restrict__ keys2, const int* __restrict__ inv1,
                         int* __restrict__ g2, const float* __restrict__ pts,
                         const int* __restrict__ vox, const int* __restrict__ numbs,
                         float* __restrict__ out_pts, float* __restrict__ out_vox,
                         float* __restrict__ out_nb, int n, int B) {
  int t = blockIdx.x * blockDim.x + threadIdx.x;
  if (t >= n) return;
  int s = (int)(keys2[t] & 0x3FFFFULL);
  g2[t] = inv1[s];
  out_pts[t * 3 + 0] = pts[s * 3 + 0];
  out_pts[t * 3 + 1] = pts[s * 3 + 1];
  out_pts[t * 3 + 2] = pts[s * 3 + 2];
  const int4 v = ((const int4*)vox)[s];
  out_vox[t * 4 + 0] = (float)v.x;
  out_vox[t * 4 + 1] = (float)v.y;
  out_vox[t * 4 + 2] = (float)v.z;
  out_vox[t * 4 + 3] = (float)v.w;
  if (t < B) out_nb[t] = (float)numbs[t];
}

// ======================= weight folding (f16, transposed) =======================
__global__ void prep_all(const float* __restrict__ Wq1, const float* __restrict__ Wk1,
                         const float* __restrict__ Wv1, const float* __restrict__ Wo1,
                         const float* __restrict__ Wout1,
                         const float* __restrict__ Wq2, const float* __restrict__ Wk2,
                         const float* __restrict__ Wv2, const float* __restrict__ Wo2,
                         const float* __restrict__ Wout2,
                         f16* __restrict__ A1a, f16* __restrict__ A2a, f16* __restrict__ A3a,
                         f16* __restrict__ A1b, f16* __restrict__ A2b, f16* __restrict__ A3b) {
  const int idx = blockIdx.x * blockDim.x + threadIdx.x;   // 16384 threads
  if (idx < 4096) {
    const int a = idx >> 6, b = idx & 63;
    float s1 = 0.f, s2 = 0.f;
    for (int c = 0; c < 64; c++) {
      s1 = fmaf(Wq1[b * 64 + c], Wk1[a * 64 + c], s1);
      s2 = fmaf(Wv1[b * 64 + c], Wo1[c * 64 + a], s2);
    }
    A1a[idx] = (f16)(s1 * 0.125f);
    A2a[idx] = (f16)s2;
  }
  if (idx < 8192) {
    const int o = idx >> 6, c = idx & 63;
    A3a[idx] = (f16)Wout1[c * 128 + o];
  }
  {
    const int a = idx >> 7, b = idx & 127;
    float s1 = 0.f, s2 = 0.f;
    for (int c = 0; c < 128; c++) {
      s1 = fmaf(Wq2[b * 128 + c], Wk2[a * 128 + c], s1);
      s2 = fmaf(Wv2[b * 128 + c], Wo2[c * 128 + a], s2);
    }
    A1b[idx] = (f16)(s1 * 0.08838834764831845f);
    A2b[idx] = (f16)s2;
    A3b[idx] = (f16)Wout2[b * 128 + a];
  }
}

// ======================= MFMA attention block (8-wave fine partition) =========
__device__ __forceinline__ int swzb(int row) {
  return (((row & 7) ^ (((row >> 3) & 3) << 1)) << 4);
}

template<int M, int K, int AMODE>
__device__ __forceinline__ void stage8(const f16* __restrict__ Ag,
                                       const f16* __restrict__ lA,
                                       const f16* __restrict__ lB,
                                       int w, int lane,
                                       f32x4 (&acc)[(M / 16) * 4 / 8]) {
  constexpr int NPW = (M / 16) * 4 / 8;
  constexpr int KT = K / 32;
  const int lr = lane & 15, lk = lane >> 4;
  const int ct = (w * NPW) >> 2;
  const int qt0 = (w * NPW) & 3;
  const int c = ct * 16 + lr;
  f16x8 Af[KT];
  #pragma unroll
  for (int kt = 0; kt < KT; kt++) {
    const int k0 = kt * 32 + lk * 8;
    if (AMODE == 0) {
      Af[kt] = *(const f16x8*)(Ag + (size_t)c * K + k0);
    } else if (AMODE == 1) {
      Af[kt] = *(const f16x8*)((const char*)lA + (((c * K + k0) * 2) ^ swzb(c)));
    } else {
      f16x8 a;
      #pragma unroll
      for (int e = 0; e < 8; e++) {
        const int j = k0 + e;
        a[e] = *(const f16*)((const char*)lA + (((j * M + c) * 2) ^ swzb(j)));
      }
      Af[kt] = a;
    }
  }
  #pragma unroll
  for (int i = 0; i < NPW; i++) {
    const int q = lr + (qt0 + i) * 16;
    #pragma unroll
    for (int kt = 0; kt < KT; kt++) {
      const int k0 = kt * 32 + lk * 8;
      const f16x8 Bf = *(const f16x8*)((const char*)lB + (((q * K + k0) * 2) ^ swzb(q)));
      acc[i] = __builtin_amdgcn_mfma_f32_16x16x32_f16(Af[kt], Bf, acc[i], 0, 0, 0);
    }
  }
}

template<int RL, bool RELU>
__device__ __forceinline__ void store8(f16* __restrict__ dst, int ct, int qt,
                                       int lane, f32x4 v) {
  const int lr = lane & 15, lk = lane >> 4;
  const int q = lr + qt * 16;
  const int c0 = ct * 16 + lk * 4;
  f16x4 o;
  #pragma unroll
  for (int r = 0; r < 4; r++) {
    float x = v[r];
    if (RELU) x = fmaxf(x, 0.f);
    o[r] = (f16)x;
  }
  *(f16x4*)((char*)dst + (((q * RL + c0) * 2) ^ swzb(q))) = o;
}

template<int C, bool X16, bool OUT16>
__global__ __launch_bounds__(512, 8) void block_mfma(
    const int* __restrict__ idx_x, const float* __restrict__ ptsP,
    const void* __restrict__ xsrc,
    const float* __restrict__ Wpos, const float* __restrict__ bpos,
    const f16* __restrict__ A1, const f16* __restrict__ A2, const f16* __restrict__ A3,
    void* __restrict__ outp) {
  constexpr int NPWC = C / 32;             // tiles/wave for M=C stages
  extern __shared__ char smem[];
  f16* bufH = (f16*)smem;            // [64][C] h -> later o2r
  f16* bufT = bufH + 64 * C;         // [64][C] t1 -> later t2
  f16* scH  = bufT + 64 * C;         // [64][64] f16 scores -> attn

  const int g = blockIdx.x;
  const int t = threadIdx.x;
  const int lane = t & 63;
  const int w = t >> 6;
  const int lr = lane & 15, lk = lane >> 4;
  const int q8 = t >> 3, qq = t & 7;       // h-build / softmax: 8 threads per row

  // ---- h = x * ((p-mean)@Wpos + bpos) -> bufH ----
  {
    const int sx = idx_x[g * 64 + q8];
    float mx = ptsP[(g * 64 + lane) * 3 + 0];
    float my = ptsP[(g * 64 + lane) * 3 + 1];
    float mz = ptsP[(g * 64 + lane) * 3 + 2];
    #pragma unroll
    for (int o = 32; o > 0; o >>= 1) {
      mx += __shfl_xor(mx, o); my += __shfl_xor(my, o); mz += __shfl_xor(mz, o);
    }
    mx *= (1.f / 64.f); my *= (1.f / 64.f); mz *= (1.f / 64.f);
    const float d0 = ptsP[(g * 64 + q8) * 3 + 0] - mx;
    const float d1 = ptsP[(g * 64 + q8) * 3 + 1] - my;
    const float d2 = ptsP[(g * 64 + q8) * 3 + 2] - mz;
    #pragma unroll
    for (int i = 0; i < C / 64; i++) {
      const int c0 = qq * (C / 8) + i * 8;
      float xa[8];
      if constexpr (X16) {
        f16x8 xr = *(const f16x8*)((const f16*)xsrc + (size_t)sx * C + c0);
        #pragma unroll
        for (int j = 0; j < 8; j++) xa[j] = (float)xr[j];
      } else {
        float4 x0 = *(const float4*)((const float*)xsrc + (size_t)sx * C + c0);
        float4 x1 = *(const float4*)((const float*)xsrc + (size_t)sx * C + c0 + 4);
        xa[0] = x0.x; xa[1] = x0.y; xa[2] = x0.z; xa[3] = x0.w;
        xa[4] = x1.x; xa[5] = x1.y; xa[6] = x1.z; xa[7] = x1.w;
      }
      f16x8 hv;
      #pragma unroll
      for (int jj = 0; jj < 8; jj += 4) {
        const float4 w0 = *(const float4*)(Wpos + 0 * C + c0 + jj);
        const float4 w1 = *(const float4*)(Wpos + 1 * C + c0 + jj);
        const float4 w2 = *(const float4*)(Wpos + 2 * C + c0 + jj);
        const float4 bb = *(const float4*)(bpos + c0 + jj);
        hv[jj + 0] = (f16)(xa[jj + 0] * fmaf(d0, w0.x, fmaf(d1, w1.x, fmaf(d2, w2.x, bb.x))));
        hv[jj + 1] = (f16)(xa[jj + 1] * fmaf(d0, w0.y, fmaf(d1, w1.y, fmaf(d2, w2.y, bb.y))));
        hv[jj + 2] = (f16)(xa[jj + 2] * fmaf(d0, w0.z, fmaf(d1, w1.z, fmaf(d2, w2.z, bb.z))));
        hv[jj + 3] = (f16)(xa[jj + 3] * fmaf(d0, w0.w, fmaf(d1, w1.w, fmaf(d2, w2.w, bb.w))));
      }
      *(f16x8*)((char*)bufH + (((q8 * C + c0) * 2) ^ swzb(q8))) = hv;
    }
  }
  __syncthreads();

  // ---- m1: t1[q][c] (wave w: 16-col slice) -> bufT ----
  {
    f32x4 acc[NPWC] = {};
    stage8<C, C, 0>(A1, nullptr, bufH, w, lane, acc);
    const int ct = (w * NPWC) >> 2, qt0 = (w * NPWC) & 3;
    #pragma unroll
    for (int i = 0; i < NPWC; i++) store8<C, false>(bufT, ct, qt0 + i, lane, acc[i]);
  }
  __syncthreads();

  // ---- m3: sc[q][j] (2 tiles/wave) -> scH ----
  {
    f32x4 acc[2] = {};
    stage8<64, C, 1>(nullptr, bufH, bufT, w, lane, acc);
    const int ct = (w * 2) >> 2, qt0 = (w * 2) & 3;
    #pragma unroll
    for (int i = 0; i < 2; i++) store8<64, false>(scH, ct, qt0 + i, lane, acc[i]);
  }
  __syncthreads();

  // ---- softmax rows of sc (8 threads/row, shfl groups of 8) ----
  {
    f16x8 x8 = *(const f16x8*)((const char*)scH + (((q8 * 64 + qq * 8) * 2) ^ swzb(q8)));
    float v[8];
    float mxv = -3.0e38f;
    #pragma unroll
    for (int j = 0; j < 8; j++) {
      v[j] = (float)x8[j];
      mxv = fmaxf(mxv, v[j]);
    }
    mxv = fmaxf(mxv, __shfl_xor(mxv, 1));
    mxv = fmaxf(mxv, __shfl_xor(mxv, 2));
    mxv = fmaxf(mxv, __shfl_xor(mxv, 4));
    float s = 0.f;
    #pragma unroll
    for (int j = 0; j < 8; j++) { v[j] = __expf(v[j] - mxv); s += v[j]; }
    s += __shfl_xor(s, 1);
    s += __shfl_xor(s, 2);
    s += __shfl_xor(s, 4);
    const float inv = 1.f / s;
    f16x8 pk;
    #pragma unroll
    for (int j = 0; j < 8; j++) pk[j] = (f16)(v[j] * inv);
    *(f16x8*)((char*)scH + (((q8 * 64 + qq * 8) * 2) ^ swzb(q8))) = pk;
  }
  __syncthreads();

  // ---- m4: t2[q][c] = sum_j h[j][c] attn[q][j] -> bufT ----
  {
    f32x4 acc[NPWC] = {};
    stage8<C, 64, 2>(nullptr, bufH, scH, w, lane, acc);
    const int ct = (w * NPWC) >> 2, qt0 = (w * NPWC) & 3;
    #pragma unroll
    for (int i = 0; i < NPWC; i++) store8<C, false>(bufT, ct, qt0 + i, lane, acc[i]);
  }
  __syncthreads();

  // ---- m5: o2r[q][c] = relu(...) -> bufH ----
  {
    f32x4 acc[NPWC] = {};
    stage8<C, C, 0>(A2, nullptr, bufT, w, lane, acc);
    const int ct = (w * NPWC) >> 2, qt0 = (w * NPWC) & 3;
    #pragma unroll
    for (int i = 0; i < NPWC; i++) store8<C, true>(bufH, ct, qt0 + i, lane, acc[i]);
  }
  __syncthreads();

  // ---- m6: y[q][o] -> global (M=128: wave w = 16-col slice ot=w) ----
  {
    f32x4 acc[4] = {};
    stage8<128, C, 0>(A3, nullptr, bufH, w, lane, acc);
    #pragma unroll
    for (int i = 0; i < 4; i++) {
      const int qr = lr + i * 16;
      const int o0 = w * 16 + lk * 4;
      const size_t row = (size_t)g * 64 + qr;
      if (OUT16) {
        f16x4 v;
        #pragma unroll
        for (int r = 0; r < 4; r++) v[r] = (f16)acc[i][r];
        *(f16x4*)((f16*)outp + row * 128 + o0) = v;
      } else {
        *(f32x4*)((float*)outp + row * 128 + o0) = acc[i];
      }
    }
  }
}

// ======================= host =======================
extern "C" void kernel_launch(void* const* d_in, const int* in_sizes, int n_in,
                              void* d_out, int out_size, void* d_ws, size_t ws_size,
                              hipStream_t stream) {
  const int*   vox_numbs = (const int*)d_in[0];
  const int*   vox_coors = (const int*)d_in[1];
  const float* vox_feats = (const float*)d_in[2];
  const float* pts_coors = (const float*)d_in[3];
  const float* Wpos1 = (const float*)d_in[4];
  const float* bpos1 = (const float*)d_in[5];
  const float* Wq1   = (const float*)d_in[6];
  const float* Wk1   = (const float*)d_in[7];
  const float* Wv1   = (const float*)d_in[8];
  const float* Wo1   = (const float*)d_in[9];
  const float* Wout1 = (const float*)d_in[10];
  const float* Wpos2 = (const float*)d_in[11];
  const float* bpos2 = (const float*)d_in[12];
  const float* Wq2   = (const float*)d_in[13];
  const float* Wk2   = (const float*)d_in[14];
  const float* Wv2   = (const float*)d_in[15];
  const float* Wo2   = (const float*)d_in[16];
  const float* Wout2 = (const float*)d_in[17];

  const int B = in_sizes[0];
  const int n = in_sizes[1] / 4;       // 262144 = 2^18
  const int ngrp = n / 64;

  char* w = (char*)d_ws;
  auto alloc = [&](size_t bytes) {
    char* p = w;
    w += (bytes + 255) & ~(size_t)255;
    return p;
  };
  u64* keys    = (u64*)alloc((size_t)2 * n * 8);   // keys1 | keys2
  int* ind1    = (int*)alloc((size_t)n * 4);
  int* inv1    = (int*)alloc((size_t)n * 4);
  int* g2      = (int*)alloc((size_t)n * 4);
  float* pts1p = (float*)alloc((size_t)n * 3 * 4);
  f16* A1a     = (f16*)alloc(64 * 64 * 2);
  f16* A2a     = (f16*)alloc(64 * 64 * 2);
  f16* A3a     = (f16*)alloc(128 * 64 * 2);
  f16* A1b     = (f16*)alloc(128 * 128 * 2);
  f16* A2b     = (f16*)alloc(128 * 128 * 2);
  f16* A3b     = (f16*)alloc(128 * 128 * 2);
  f16* feats1  = (f16*)alloc((size_t)n * 128 * 2);
  u64* keys2   = keys + n;

  float* out_feats = (float*)d_out;
  float* out_pts   = out_feats + (size_t)n * 128;
  float* out_vox   = out_pts + (size_t)n * 3;
  float* out_nb    = out_vox + (size_t)n * 4;

  auto f64k  = block_mfma<64,  false, true>;
  auto f128k = block_mfma<128, true,  false>;
  hipFuncSetAttribute((const void*)f64k,  hipFuncAttributeMaxDynamicSharedMemorySize, 65536);
  hipFuncSetAttribute((const void*)f128k, hipFuncAttributeMaxDynamicSharedMemorySize, 65536);

  prep_all<<<64, 256, 0, stream>>>(Wq1, Wk1, Wv1, Wo1, Wout1, Wq2, Wk2, Wv2, Wo2, Wout2,
                                   A1a, A2a, A3a, A1b, A2b, A3b);

  // ---- batch-segmented bitonic sort (2048-tiles, both orderings) ----
  int span = (B > 0) ? n / B : n;
  if (span < 4096 || (span & (span - 1)) != 0 || n % span != 0) span = n;
  const int spanm1 = span - 1;

  sort_tile0<<<2 * n / 2048, 1024, 0, stream>>>(vox_coors, keys, n, spanm1);
  for (int k = 4096; k <= span; k <<= 1) {
    int j = k >> 1;
    while (j >= 2048) {
      int lev = 1;
      while (lev < 4 && (j >> lev) >= 2048) lev++;
      const int jlow = j >> (lev - 1);
      const int nth = (2 * n) >> lev;
      bitonic_gN<<<nth / 256, 256, 0, stream>>>(keys, jlow, lev, k, spanm1);
      j = jlow >> 1;
    }
    merge_tile2<<<2 * n / 2048, 1024, 0, stream>>>(keys, k, spanm1);
  }

  extract_inv_k<<<(n + 255) / 256, 256, 0, stream>>>(keys, pts_coors, ind1, inv1, pts1p, n);
  finish_k<<<(n + 255) / 256, 256, 0, stream>>>(keys2, inv1, g2, pts_coors, vox_coors,
                                                vox_numbs, out_pts, out_vox, out_nb, n, B);

  block_mfma<64, false, true><<<ngrp, 512, 24576, stream>>>(
      ind1, pts1p, vox_feats, Wpos1, bpos1, A1a, A2a, A3a, feats1);
  block_mfma<128, true, false><<<ngrp, 512, 40960, stream>>>(
      g2, out_pts, feats1, Wpos2, bpos2, A1b, A2b, A3b, out_feats);
}